// Round 8
// baseline (603.592 us; speedup 1.0000x reference)
//
#include <hip/hip_runtime.h>
#include <hip/hip_bf16.h>

#define D 64
#define BSHIFT 9
#define BW (1 << BSHIFT)          // bucket width: 512 destination nodes
#define MAXB 512                  // max buckets supported by bhist/bscan LDS

typedef __attribute__((ext_vector_type(8))) short bf16x8;   // 8 bf16 in 4 VGPRs
typedef __attribute__((ext_vector_type(4))) float f32x4;

__device__ __forceinline__ short f2bf(float f) {
    __hip_bfloat16 h = __float2bfloat16(f);
    return *reinterpret_cast<short*>(&h);
}

// ---------------------------------------------------------------------------
// K1: per-node message MLP via MFMA.  m[v] = relu(x[v]@W1 + b1)@W2 + b2
// ---------------------------------------------------------------------------
__global__ __launch_bounds__(256) void msg_kernel(
    const float* __restrict__ x,
    const float* __restrict__ w1, const float* __restrict__ b1,
    const float* __restrict__ w2, const float* __restrict__ b2,
    float* __restrict__ m, int n_nodes)
{
    __shared__ __align__(16) __hip_bfloat16 sH[4][16 * 72];

    const int lane = threadIdx.x & 63;
    const int wslot = threadIdx.x >> 6;
    const int mr   = lane & 15;
    const int quad = lane >> 4;

    bf16x8 w1f[2][4], w2f[2][4];
    float  b1v[4], b2v[4];
#pragma unroll
    for (int ks = 0; ks < 2; ++ks)
#pragma unroll
        for (int nb = 0; nb < 4; ++nb) {
            bf16x8 f1, f2;
#pragma unroll
            for (int j = 0; j < 8; ++j) {
                int k = ks * 32 + quad * 8 + j;
                f1[j] = f2bf(w1[k * D + nb * 16 + mr]);
                f2[j] = f2bf(w2[k * D + nb * 16 + mr]);
            }
            w1f[ks][nb] = f1;
            w2f[ks][nb] = f2;
        }
#pragma unroll
    for (int nb = 0; nb < 4; ++nb) {
        b1v[nb] = b1[nb * 16 + mr];
        b2v[nb] = b2[nb * 16 + mr];
    }

    __hip_bfloat16* Hw = sH[wslot];
    const int wid    = (blockIdx.x * blockDim.x + threadIdx.x) >> 6;
    const int nwaves = (gridDim.x * blockDim.x) >> 6;
    const int ntiles = (n_nodes + 15) >> 4;

    for (int t = wid; t < ntiles; t += nwaves) {
        const int v0 = t * 16;
        int vr = v0 + mr;
        if (vr >= n_nodes) vr = n_nodes - 1;

        bf16x8 a[2];
#pragma unroll
        for (int ks = 0; ks < 2; ++ks) {
            const float* p = x + (size_t)vr * D + ks * 32 + quad * 8;
            float4 lo = *(const float4*)p;
            float4 hi = *(const float4*)(p + 4);
            bf16x8 f;
            f[0] = f2bf(lo.x); f[1] = f2bf(lo.y); f[2] = f2bf(lo.z); f[3] = f2bf(lo.w);
            f[4] = f2bf(hi.x); f[5] = f2bf(hi.y); f[6] = f2bf(hi.z); f[7] = f2bf(hi.w);
            a[ks] = f;
        }

#pragma unroll
        for (int nb = 0; nb < 4; ++nb) {
            f32x4 acc = {0.f, 0.f, 0.f, 0.f};
            acc = __builtin_amdgcn_mfma_f32_16x16x32_bf16(a[0], w1f[0][nb], acc, 0, 0, 0);
            acc = __builtin_amdgcn_mfma_f32_16x16x32_bf16(a[1], w1f[1][nb], acc, 0, 0, 0);
#pragma unroll
            for (int r = 0; r < 4; ++r) {
                float hv = fmaxf(acc[r] + b1v[nb], 0.f);
                Hw[(quad * 4 + r) * 72 + nb * 16 + mr] = __float2bfloat16(hv);
            }
        }

        bf16x8 h[2];
#pragma unroll
        for (int ks = 0; ks < 2; ++ks)
            h[ks] = *(const bf16x8*)&Hw[mr * 72 + ks * 32 + quad * 8];

#pragma unroll
        for (int nb = 0; nb < 4; ++nb) {
            f32x4 acc = {0.f, 0.f, 0.f, 0.f};
            acc = __builtin_amdgcn_mfma_f32_16x16x32_bf16(h[0], w2f[0][nb], acc, 0, 0, 0);
            acc = __builtin_amdgcn_mfma_f32_16x16x32_bf16(h[1], w2f[1][nb], acc, 0, 0, 0);
#pragma unroll
            for (int r = 0; r < 4; ++r) {
                int vrow = v0 + quad * 4 + r;
                if (vrow < n_nodes)
                    m[(size_t)vrow * D + nb * 16 + mr] = acc[r] + b2v[nb];
            }
        }
    }
}

// ---------------------------------------------------------------------------
// Bucket-level CSR: bhist -> bscan -> bin (packed (c_local,src) per bucket).
// ---------------------------------------------------------------------------
__global__ __launch_bounds__(256) void bhist_kernel(
    const int* __restrict__ col, int* __restrict__ bcount,
    int n_edges, int nbuckets)
{
    __shared__ int h[MAXB];
    for (int i = threadIdx.x; i < nbuckets; i += 256) h[i] = 0;
    __syncthreads();
    for (int e = blockIdx.x * blockDim.x + threadIdx.x; e < n_edges;
         e += gridDim.x * blockDim.x)
        atomicAdd(&h[col[e] >> BSHIFT], 1);
    __syncthreads();
    for (int i = threadIdx.x; i < nbuckets; i += 256)
        if (h[i]) atomicAdd(&bcount[i], h[i]);
}

// 1 block: exclusive scan of bcount -> gstart (kept) and gcur (consumed by bin).
__global__ __launch_bounds__(512) void bscan_kernel(
    const int* __restrict__ bcount, int* __restrict__ gstart,
    int* __restrict__ gcur, int nbuckets)
{
    __shared__ int tmp[512];
    const int t = threadIdx.x;
    int v = (t < nbuckets) ? bcount[t] : 0;
    tmp[t] = v;
    __syncthreads();
    for (int off = 1; off < 512; off <<= 1) {
        int u = (t >= off) ? tmp[t - off] : 0;
        __syncthreads();
        tmp[t] += u;
        __syncthreads();
    }
    if (t < nbuckets) {
        int e = tmp[t] - v;   // exclusive
        gstart[t] = e;
        gcur[t]   = e;
    }
}

// Bin edges by destination bucket into packed u32: (c_local<<17) | src.
__global__ __launch_bounds__(256) void bin_kernel(
    const int* __restrict__ row, const int* __restrict__ col,
    int* __restrict__ gcur, unsigned int* __restrict__ tmp,
    int n_edges, int nbuckets, int chunk)
{
    __shared__ int hist[MAXB], base[MAXB], lcur[MAXB];
    const int t = threadIdx.x;
    const int e0 = blockIdx.x * chunk;
    const int e1 = min(e0 + chunk, n_edges);

    for (int i = t; i < nbuckets; i += 256) hist[i] = 0;
    __syncthreads();
    for (int e = e0 + t; e < e1; e += 256)
        atomicAdd(&hist[col[e] >> BSHIFT], 1);
    __syncthreads();
    for (int i = t; i < nbuckets; i += 256) {
        base[i] = hist[i] ? atomicAdd(&gcur[i], hist[i]) : 0;
        lcur[i] = 0;
    }
    __syncthreads();
    for (int e = e0 + t; e < e1; e += 256) {
        int c = col[e];
        int b = c >> BSHIFT;
        int loc = atomicAdd(&lcur[b], 1);
        unsigned int val = ((unsigned int)(c & (BW - 1)) << 17)
                         | (unsigned int)row[e];
        tmp[base[b] + loc] = val;
    }
}

// ---------------------------------------------------------------------------
// K2: fused fill+gather.  One block per bucket; 512-node x 64-feat fp32 agg
// tile in LDS (128 KB); stream packed edges, 64-lane m-row loads (4-deep ILP),
// LDS atomic accumulate (2-way bank alias = free), coalesced tile writeback.
// ---------------------------------------------------------------------------
__global__ __launch_bounds__(512) void bucket_gather_kernel(
    const int* __restrict__ gstart, const unsigned int* __restrict__ tmp,
    const float* __restrict__ m, float* __restrict__ agg,
    int n_nodes, int n_edges, int nbuckets)
{
    __shared__ __align__(16) float tile[BW * D];   // 128 KB

    const int b     = blockIdx.x;
    const int lane  = threadIdx.x & 63;
    const int wv    = threadIdx.x >> 6;            // 0..7
    const int vbase = b << BSHIFT;
    const int nloc  = min(BW, n_nodes - vbase);

    // zero tile (float4)
    float4* t4 = (float4*)tile;
    for (int i = threadIdx.x; i < BW * D / 4; i += 512)
        t4[i] = make_float4(0.f, 0.f, 0.f, 0.f);
    __syncthreads();

    const int start = gstart[b];
    const int end   = (b + 1 < nbuckets) ? gstart[b + 1] : n_edges;

    for (int i0 = start + wv * 4; i0 < end; i0 += 32) {
        const int n4 = min(4, end - i0);
        unsigned int pv = 0;
        if (lane < n4) pv = tmp[i0 + lane];
        unsigned int u0 = __builtin_amdgcn_readlane(pv, 0);
        unsigned int u1 = __builtin_amdgcn_readlane(pv, 1);
        unsigned int u2 = __builtin_amdgcn_readlane(pv, 2);
        unsigned int u3 = __builtin_amdgcn_readlane(pv, 3);

        float v0 = 0.f, v1 = 0.f, v2 = 0.f, v3 = 0.f;
        v0 = m[(size_t)(u0 & 0x1FFFFu) * D + lane];
        if (n4 > 1) v1 = m[(size_t)(u1 & 0x1FFFFu) * D + lane];
        if (n4 > 2) v2 = m[(size_t)(u2 & 0x1FFFFu) * D + lane];
        if (n4 > 3) v3 = m[(size_t)(u3 & 0x1FFFFu) * D + lane];

        atomicAdd(&tile[(u0 >> 17) * D + lane], v0);
        if (n4 > 1) atomicAdd(&tile[(u1 >> 17) * D + lane], v1);
        if (n4 > 2) atomicAdd(&tile[(u2 >> 17) * D + lane], v2);
        if (n4 > 3) atomicAdd(&tile[(u3 >> 17) * D + lane], v3);
    }
    __syncthreads();

    // coalesced writeback of nloc rows
    float4* a4 = (float4*)(agg + (size_t)vbase * D);
    for (int i = threadIdx.x; i < nloc * D / 4; i += 512)
        a4[i] = t4[i];
}

// ---------------------------------------------------------------------------
// Fallback scatter (ws too small / shape out of range): fp32 atomics.
// ---------------------------------------------------------------------------
__global__ __launch_bounds__(256) void scatter_kernel(
    const int* __restrict__ row, const int* __restrict__ col,
    const float* __restrict__ m, float* __restrict__ agg, int n_edges)
{
    const int lane = threadIdx.x & 63;
    const int wid  = (blockIdx.x * blockDim.x + threadIdx.x) >> 6;
    const int base = wid * 64;
    if (base >= n_edges) return;
    const int cnt = min(64, n_edges - base);

    int my_r = 0, my_c = 0;
    if (lane < cnt) { my_r = row[base + lane]; my_c = col[base + lane]; }

    for (int j = 0; j < cnt; ++j) {
        int r = __builtin_amdgcn_readlane(my_r, j);
        int c = __builtin_amdgcn_readlane(my_c, j);
        float v = m[(size_t)r * D + lane];
        atomicAdd(&agg[(size_t)c * D + lane], v);
    }
}

// ---------------------------------------------------------------------------
// K3: output MLP via MFMA.  out[v] = relu([x[v],agg[v]]@OW1 + ob1)@OW2 + ob2
// ---------------------------------------------------------------------------
__global__ __launch_bounds__(256) void out_kernel(
    const float* __restrict__ x, const float* __restrict__ agg,
    const float* __restrict__ w1, const float* __restrict__ b1,
    const float* __restrict__ w2, const float* __restrict__ b2,
    float* __restrict__ out, int n_nodes)
{
    __shared__ __align__(16) __hip_bfloat16 sH[4][16 * 72];

    const int lane = threadIdx.x & 63;
    const int wslot = threadIdx.x >> 6;
    const int mr   = lane & 15;
    const int quad = lane >> 4;

    bf16x8 w1f[4][4], w2f[2][4];
    float  b1v[4], b2v[4];
#pragma unroll
    for (int ks = 0; ks < 4; ++ks)
#pragma unroll
        for (int nb = 0; nb < 4; ++nb) {
            bf16x8 f;
#pragma unroll
            for (int j = 0; j < 8; ++j) {
                int k = ks * 32 + quad * 8 + j;
                f[j] = f2bf(w1[k * D + nb * 16 + mr]);
            }
            w1f[ks][nb] = f;
        }
#pragma unroll
    for (int ks = 0; ks < 2; ++ks)
#pragma unroll
        for (int nb = 0; nb < 4; ++nb) {
            bf16x8 f;
#pragma unroll
            for (int j = 0; j < 8; ++j) {
                int k = ks * 32 + quad * 8 + j;
                f[j] = f2bf(w2[k * D + nb * 16 + mr]);
            }
            w2f[ks][nb] = f;
        }
#pragma unroll
    for (int nb = 0; nb < 4; ++nb) {
        b1v[nb] = b1[nb * 16 + mr];
        b2v[nb] = b2[nb * 16 + mr];
    }

    __hip_bfloat16* Hw = sH[wslot];
    const int wid    = (blockIdx.x * blockDim.x + threadIdx.x) >> 6;
    const int nwaves = (gridDim.x * blockDim.x) >> 6;
    const int ntiles = (n_nodes + 15) >> 4;

    for (int t = wid; t < ntiles; t += nwaves) {
        const int v0 = t * 16;
        int vr = v0 + mr;
        if (vr >= n_nodes) vr = n_nodes - 1;

        bf16x8 a[4];
#pragma unroll
        for (int ks = 0; ks < 4; ++ks) {
            const float* src = (ks < 2) ? (x + (size_t)vr * D + ks * 32)
                                        : (agg + (size_t)vr * D + (ks - 2) * 32);
            const float* p = src + quad * 8;
            float4 lo = *(const float4*)p;
            float4 hi = *(const float4*)(p + 4);
            bf16x8 f;
            f[0] = f2bf(lo.x); f[1] = f2bf(lo.y); f[2] = f2bf(lo.z); f[3] = f2bf(lo.w);
            f[4] = f2bf(hi.x); f[5] = f2bf(hi.y); f[6] = f2bf(hi.z); f[7] = f2bf(hi.w);
            a[ks] = f;
        }

#pragma unroll
        for (int nb = 0; nb < 4; ++nb) {
            f32x4 acc = {0.f, 0.f, 0.f, 0.f};
#pragma unroll
            for (int ks = 0; ks < 4; ++ks)
                acc = __builtin_amdgcn_mfma_f32_16x16x32_bf16(a[ks], w1f[ks][nb], acc, 0, 0, 0);
#pragma unroll
            for (int r = 0; r < 4; ++r) {
                float hv = fmaxf(acc[r] + b1v[nb], 0.f);
                Hw[(quad * 4 + r) * 72 + nb * 16 + mr] = __float2bfloat16(hv);
            }
        }

        bf16x8 h[2];
#pragma unroll
        for (int ks = 0; ks < 2; ++ks)
            h[ks] = *(const bf16x8*)&Hw[mr * 72 + ks * 32 + quad * 8];

#pragma unroll
        for (int nb = 0; nb < 4; ++nb) {
            f32x4 acc = {0.f, 0.f, 0.f, 0.f};
            acc = __builtin_amdgcn_mfma_f32_16x16x32_bf16(h[0], w2f[0][nb], acc, 0, 0, 0);
            acc = __builtin_amdgcn_mfma_f32_16x16x32_bf16(h[1], w2f[1][nb], acc, 0, 0, 0);
#pragma unroll
            for (int r = 0; r < 4; ++r) {
                int vrow = v0 + quad * 4 + r;
                if (vrow < n_nodes)
                    out[(size_t)vrow * D + nb * 16 + mr] = acc[r] + b2v[nb];
            }
        }
    }
}

// ---------------------------------------------------------------------------
extern "C" void kernel_launch(void* const* d_in, const int* in_sizes, int n_in,
                              void* d_out, int out_size, void* d_ws, size_t ws_size,
                              hipStream_t stream) {
    const float* x   = (const float*)d_in[0];
    const int*   ei  = (const int*)d_in[1];
    // d_in[2] = batch (unused)
    const float* mw1 = (const float*)d_in[3];
    const float* mb1 = (const float*)d_in[4];
    const float* mw2 = (const float*)d_in[5];
    const float* mb2 = (const float*)d_in[6];
    const float* ow1 = (const float*)d_in[7];
    const float* ob1 = (const float*)d_in[8];
    const float* ow2 = (const float*)d_in[9];
    const float* ob2 = (const float*)d_in[10];

    const int n_nodes = in_sizes[0] / D;        // 100000
    const int n_edges = in_sizes[1] / 2;        // 1000000
    const int* row = ei;                        // edge_index[0]
    const int* col = ei + n_edges;              // edge_index[1]

    const int nbuckets = (n_nodes + BW - 1) >> BSHIFT;   // 196

    // ws layout
    float* m   = (float*)d_ws;                        // [n_nodes*64] f32
    float* agg = m + (size_t)n_nodes * D;             // [n_nodes*64] f32
    unsigned int* tmp = (unsigned int*)(agg + (size_t)n_nodes * D); // [n_edges]
    int* bcount = (int*)(tmp + n_edges);              // [nbuckets]
    int* gstart = bcount + nbuckets;                  // [nbuckets]
    int* gcur   = gstart + nbuckets;                  // [nbuckets]
    const size_t need = (size_t)n_nodes * D * 8 + (size_t)n_edges * 4
                      + (size_t)nbuckets * 12;

    const int ntiles = (n_nodes + 15) / 16;
    const int nblk   = (ntiles + 3) / 4;

    msg_kernel<<<nblk, 256, 0, stream>>>(x, mw1, mb1, mw2, mb2, m, n_nodes);

    const bool shape_ok = (n_nodes < (1 << 17)) && (nbuckets <= MAXB);

    if (ws_size >= need && shape_ok) {
        hipMemsetAsync(bcount, 0, (size_t)nbuckets * sizeof(int), stream);
        bhist_kernel<<<256, 256, 0, stream>>>(col, bcount, n_edges, nbuckets);
        bscan_kernel<<<1, 512, 0, stream>>>(bcount, gstart, gcur, nbuckets);
        const int nbbin = 128;
        const int chunk = (n_edges + nbbin - 1) / nbbin;
        bin_kernel<<<nbbin, 256, 0, stream>>>(row, col, gcur, tmp,
                                              n_edges, nbuckets, chunk);
        bucket_gather_kernel<<<nbuckets, 512, 0, stream>>>(gstart, tmp, m, agg,
                                                           n_nodes, n_edges, nbuckets);
    } else {
        hipMemsetAsync(agg, 0, (size_t)n_nodes * D * sizeof(float), stream);
        const int nwaves_s = (n_edges + 63) / 64;
        scatter_kernel<<<(nwaves_s + 3) / 4, 256, 0, stream>>>(row, col, m, agg, n_edges);
    }

    out_kernel<<<nblk, 256, 0, stream>>>(x, agg, ow1, ob1, ow2, ob2,
                                         (float*)d_out, n_nodes);
}

// Round 9
// 597.352 us; speedup vs baseline: 1.0104x; 1.0104x over previous
//
#include <hip/hip_runtime.h>
#include <hip/hip_bf16.h>

#define D 64
#define BSHIFT 7
#define BW (1 << BSHIFT)          // bucket width: 128 destination nodes (32 KB tile)
#define MAXB 1024                 // max buckets (bscan is a 1024-thread scan)

typedef __attribute__((ext_vector_type(8))) short bf16x8;   // 8 bf16 in 4 VGPRs
typedef __attribute__((ext_vector_type(4))) float f32x4;

__device__ __forceinline__ short f2bf(float f) {
    __hip_bfloat16 h = __float2bfloat16(f);
    return *reinterpret_cast<short*>(&h);
}

// ---------------------------------------------------------------------------
// K1: per-node message MLP via MFMA.  m[v] = relu(x[v]@W1 + b1)@W2 + b2
// Output m stored as bf16 (halves downstream random-read bytes).
// ---------------------------------------------------------------------------
__global__ __launch_bounds__(256) void msg_kernel(
    const float* __restrict__ x,
    const float* __restrict__ w1, const float* __restrict__ b1,
    const float* __restrict__ w2, const float* __restrict__ b2,
    __hip_bfloat16* __restrict__ m, int n_nodes)
{
    __shared__ __align__(16) __hip_bfloat16 sH[4][16 * 72];

    const int lane = threadIdx.x & 63;
    const int wslot = threadIdx.x >> 6;
    const int mr   = lane & 15;
    const int quad = lane >> 4;

    bf16x8 w1f[2][4], w2f[2][4];
    float  b1v[4], b2v[4];
#pragma unroll
    for (int ks = 0; ks < 2; ++ks)
#pragma unroll
        for (int nb = 0; nb < 4; ++nb) {
            bf16x8 f1, f2;
#pragma unroll
            for (int j = 0; j < 8; ++j) {
                int k = ks * 32 + quad * 8 + j;
                f1[j] = f2bf(w1[k * D + nb * 16 + mr]);
                f2[j] = f2bf(w2[k * D + nb * 16 + mr]);
            }
            w1f[ks][nb] = f1;
            w2f[ks][nb] = f2;
        }
#pragma unroll
    for (int nb = 0; nb < 4; ++nb) {
        b1v[nb] = b1[nb * 16 + mr];
        b2v[nb] = b2[nb * 16 + mr];
    }

    __hip_bfloat16* Hw = sH[wslot];
    const int wid    = (blockIdx.x * blockDim.x + threadIdx.x) >> 6;
    const int nwaves = (gridDim.x * blockDim.x) >> 6;
    const int ntiles = (n_nodes + 15) >> 4;

    for (int t = wid; t < ntiles; t += nwaves) {
        const int v0 = t * 16;
        int vr = v0 + mr;
        if (vr >= n_nodes) vr = n_nodes - 1;

        bf16x8 a[2];
#pragma unroll
        for (int ks = 0; ks < 2; ++ks) {
            const float* p = x + (size_t)vr * D + ks * 32 + quad * 8;
            float4 lo = *(const float4*)p;
            float4 hi = *(const float4*)(p + 4);
            bf16x8 f;
            f[0] = f2bf(lo.x); f[1] = f2bf(lo.y); f[2] = f2bf(lo.z); f[3] = f2bf(lo.w);
            f[4] = f2bf(hi.x); f[5] = f2bf(hi.y); f[6] = f2bf(hi.z); f[7] = f2bf(hi.w);
            a[ks] = f;
        }

#pragma unroll
        for (int nb = 0; nb < 4; ++nb) {
            f32x4 acc = {0.f, 0.f, 0.f, 0.f};
            acc = __builtin_amdgcn_mfma_f32_16x16x32_bf16(a[0], w1f[0][nb], acc, 0, 0, 0);
            acc = __builtin_amdgcn_mfma_f32_16x16x32_bf16(a[1], w1f[1][nb], acc, 0, 0, 0);
#pragma unroll
            for (int r = 0; r < 4; ++r) {
                float hv = fmaxf(acc[r] + b1v[nb], 0.f);
                Hw[(quad * 4 + r) * 72 + nb * 16 + mr] = __float2bfloat16(hv);
            }
        }

        bf16x8 h[2];
#pragma unroll
        for (int ks = 0; ks < 2; ++ks)
            h[ks] = *(const bf16x8*)&Hw[mr * 72 + ks * 32 + quad * 8];

#pragma unroll
        for (int nb = 0; nb < 4; ++nb) {
            f32x4 acc = {0.f, 0.f, 0.f, 0.f};
            acc = __builtin_amdgcn_mfma_f32_16x16x32_bf16(h[0], w2f[0][nb], acc, 0, 0, 0);
            acc = __builtin_amdgcn_mfma_f32_16x16x32_bf16(h[1], w2f[1][nb], acc, 0, 0, 0);
#pragma unroll
            for (int r = 0; r < 4; ++r) {
                int vrow = v0 + quad * 4 + r;
                if (vrow < n_nodes)
                    m[(size_t)vrow * D + nb * 16 + mr] =
                        __float2bfloat16(acc[r] + b2v[nb]);
            }
        }
    }
}

// ---------------------------------------------------------------------------
// Bucket-level CSR: bhist -> bscan -> bin (packed (c_local<<17)|src per bucket).
// ---------------------------------------------------------------------------
__global__ __launch_bounds__(256) void bhist_kernel(
    const int* __restrict__ col, int* __restrict__ bcount,
    int n_edges, int nbuckets)
{
    __shared__ int h[MAXB];
    for (int i = threadIdx.x; i < nbuckets; i += 256) h[i] = 0;
    __syncthreads();
    for (int e = blockIdx.x * blockDim.x + threadIdx.x; e < n_edges;
         e += gridDim.x * blockDim.x)
        atomicAdd(&h[col[e] >> BSHIFT], 1);
    __syncthreads();
    for (int i = threadIdx.x; i < nbuckets; i += 256)
        if (h[i]) atomicAdd(&bcount[i], h[i]);
}

// 1 block: exclusive scan of bcount -> gstart (kept) and gcur (consumed by bin).
__global__ __launch_bounds__(1024) void bscan_kernel(
    const int* __restrict__ bcount, int* __restrict__ gstart,
    int* __restrict__ gcur, int nbuckets)
{
    __shared__ int tmp[1024];
    const int t = threadIdx.x;
    int v = (t < nbuckets) ? bcount[t] : 0;
    tmp[t] = v;
    __syncthreads();
    for (int off = 1; off < 1024; off <<= 1) {
        int u = (t >= off) ? tmp[t - off] : 0;
        __syncthreads();
        tmp[t] += u;
        __syncthreads();
    }
    if (t < nbuckets) {
        int e = tmp[t] - v;   // exclusive
        gstart[t] = e;
        gcur[t]   = e;
    }
}

// Bin edges by destination bucket into packed u32: (c_local<<17) | src.
__global__ __launch_bounds__(256) void bin_kernel(
    const int* __restrict__ row, const int* __restrict__ col,
    int* __restrict__ gcur, unsigned int* __restrict__ tmp,
    int n_edges, int nbuckets, int chunk)
{
    __shared__ int hist[MAXB], base[MAXB], lcur[MAXB];
    const int t = threadIdx.x;
    const int e0 = blockIdx.x * chunk;
    const int e1 = min(e0 + chunk, n_edges);

    for (int i = t; i < nbuckets; i += 256) hist[i] = 0;
    __syncthreads();
    for (int e = e0 + t; e < e1; e += 256)
        atomicAdd(&hist[col[e] >> BSHIFT], 1);
    __syncthreads();
    for (int i = t; i < nbuckets; i += 256) {
        base[i] = hist[i] ? atomicAdd(&gcur[i], hist[i]) : 0;
        lcur[i] = 0;
    }
    __syncthreads();
    for (int e = e0 + t; e < e1; e += 256) {
        int c = col[e];
        int b = c >> BSHIFT;
        int loc = atomicAdd(&lcur[b], 1);
        unsigned int val = ((unsigned int)(c & (BW - 1)) << 17)
                         | (unsigned int)row[e];
        tmp[base[b] + loc] = val;
    }
}

// ---------------------------------------------------------------------------
// K2: fused fill+gather.  One block per 128-node bucket; 32 KB fp32 tile in
// LDS (5 blocks/CU fit -> real occupancy, unlike the 128 KB/1-block version).
// Stream 64 packed edges per wave-load, readlane broadcast, 4-deep ILP on the
// random bf16 m-row loads, LDS atomic accumulate (lane->bank 2-way = free),
// coalesced float4 writeback.
// ---------------------------------------------------------------------------
__global__ __launch_bounds__(256) void bucket_gather_kernel(
    const int* __restrict__ gstart, const unsigned int* __restrict__ tmp,
    const __hip_bfloat16* __restrict__ m, float* __restrict__ agg,
    int n_nodes, int n_edges, int nbuckets)
{
    __shared__ __align__(16) float tile[BW * D];   // 32 KB

    const int b     = blockIdx.x;
    const int lane  = threadIdx.x & 63;
    const int wv    = threadIdx.x >> 6;            // 0..3
    const int vbase = b << BSHIFT;
    const int nloc  = min(BW, n_nodes - vbase);

    float4* t4 = (float4*)tile;
    for (int i = threadIdx.x; i < BW * D / 4; i += 256)
        t4[i] = make_float4(0.f, 0.f, 0.f, 0.f);
    __syncthreads();

    const int start = gstart[b];
    const int end   = (b + 1 < nbuckets) ? gstart[b + 1] : n_edges;

    for (int cs = start + wv * 64; cs < end; cs += 256) {
        const int cnt = min(64, end - cs);
        unsigned int pv = 0;
        if (lane < cnt) pv = tmp[cs + lane];

        int j = 0;
        for (; j + 4 <= cnt; j += 4) {
            unsigned int u0 = __builtin_amdgcn_readlane(pv, j + 0);
            unsigned int u1 = __builtin_amdgcn_readlane(pv, j + 1);
            unsigned int u2 = __builtin_amdgcn_readlane(pv, j + 2);
            unsigned int u3 = __builtin_amdgcn_readlane(pv, j + 3);

            float v0 = (float)m[(size_t)(u0 & 0x1FFFFu) * D + lane];
            float v1 = (float)m[(size_t)(u1 & 0x1FFFFu) * D + lane];
            float v2 = (float)m[(size_t)(u2 & 0x1FFFFu) * D + lane];
            float v3 = (float)m[(size_t)(u3 & 0x1FFFFu) * D + lane];

            atomicAdd(&tile[(u0 >> 17) * D + lane], v0);
            atomicAdd(&tile[(u1 >> 17) * D + lane], v1);
            atomicAdd(&tile[(u2 >> 17) * D + lane], v2);
            atomicAdd(&tile[(u3 >> 17) * D + lane], v3);
        }
        for (; j < cnt; ++j) {
            unsigned int u = __builtin_amdgcn_readlane(pv, j);
            float v = (float)m[(size_t)(u & 0x1FFFFu) * D + lane];
            atomicAdd(&tile[(u >> 17) * D + lane], v);
        }
    }
    __syncthreads();

    float4* a4 = (float4*)(agg + (size_t)vbase * D);
    for (int i = threadIdx.x; i < nloc * D / 4; i += 256)
        a4[i] = t4[i];
}

// ---------------------------------------------------------------------------
// Fallback scatter (ws too small / shape out of range): fp32 atomics.
// ---------------------------------------------------------------------------
__global__ __launch_bounds__(256) void scatter_kernel(
    const int* __restrict__ row, const int* __restrict__ col,
    const __hip_bfloat16* __restrict__ m, float* __restrict__ agg, int n_edges)
{
    const int lane = threadIdx.x & 63;
    const int wid  = (blockIdx.x * blockDim.x + threadIdx.x) >> 6;
    const int base = wid * 64;
    if (base >= n_edges) return;
    const int cnt = min(64, n_edges - base);

    int my_r = 0, my_c = 0;
    if (lane < cnt) { my_r = row[base + lane]; my_c = col[base + lane]; }

    for (int j = 0; j < cnt; ++j) {
        int r = __builtin_amdgcn_readlane(my_r, j);
        int c = __builtin_amdgcn_readlane(my_c, j);
        float v = (float)m[(size_t)r * D + lane];
        atomicAdd(&agg[(size_t)c * D + lane], v);
    }
}

// ---------------------------------------------------------------------------
// K3: output MLP via MFMA.  out[v] = relu([x[v],agg[v]]@OW1 + ob1)@OW2 + ob2
// ---------------------------------------------------------------------------
__global__ __launch_bounds__(256) void out_kernel(
    const float* __restrict__ x, const float* __restrict__ agg,
    const float* __restrict__ w1, const float* __restrict__ b1,
    const float* __restrict__ w2, const float* __restrict__ b2,
    float* __restrict__ out, int n_nodes)
{
    __shared__ __align__(16) __hip_bfloat16 sH[4][16 * 72];

    const int lane = threadIdx.x & 63;
    const int wslot = threadIdx.x >> 6;
    const int mr   = lane & 15;
    const int quad = lane >> 4;

    bf16x8 w1f[4][4], w2f[2][4];
    float  b1v[4], b2v[4];
#pragma unroll
    for (int ks = 0; ks < 4; ++ks)
#pragma unroll
        for (int nb = 0; nb < 4; ++nb) {
            bf16x8 f;
#pragma unroll
            for (int j = 0; j < 8; ++j) {
                int k = ks * 32 + quad * 8 + j;
                f[j] = f2bf(w1[k * D + nb * 16 + mr]);
            }
            w1f[ks][nb] = f;
        }
#pragma unroll
    for (int ks = 0; ks < 2; ++ks)
#pragma unroll
        for (int nb = 0; nb < 4; ++nb) {
            bf16x8 f;
#pragma unroll
            for (int j = 0; j < 8; ++j) {
                int k = ks * 32 + quad * 8 + j;
                f[j] = f2bf(w2[k * D + nb * 16 + mr]);
            }
            w2f[ks][nb] = f;
        }
#pragma unroll
    for (int nb = 0; nb < 4; ++nb) {
        b1v[nb] = b1[nb * 16 + mr];
        b2v[nb] = b2[nb * 16 + mr];
    }

    __hip_bfloat16* Hw = sH[wslot];
    const int wid    = (blockIdx.x * blockDim.x + threadIdx.x) >> 6;
    const int nwaves = (gridDim.x * blockDim.x) >> 6;
    const int ntiles = (n_nodes + 15) >> 4;

    for (int t = wid; t < ntiles; t += nwaves) {
        const int v0 = t * 16;
        int vr = v0 + mr;
        if (vr >= n_nodes) vr = n_nodes - 1;

        bf16x8 a[4];
#pragma unroll
        for (int ks = 0; ks < 4; ++ks) {
            const float* src = (ks < 2) ? (x + (size_t)vr * D + ks * 32)
                                        : (agg + (size_t)vr * D + (ks - 2) * 32);
            const float* p = src + quad * 8;
            float4 lo = *(const float4*)p;
            float4 hi = *(const float4*)(p + 4);
            bf16x8 f;
            f[0] = f2bf(lo.x); f[1] = f2bf(lo.y); f[2] = f2bf(lo.z); f[3] = f2bf(lo.w);
            f[4] = f2bf(hi.x); f[5] = f2bf(hi.y); f[6] = f2bf(hi.z); f[7] = f2bf(hi.w);
            a[ks] = f;
        }

#pragma unroll
        for (int nb = 0; nb < 4; ++nb) {
            f32x4 acc = {0.f, 0.f, 0.f, 0.f};
#pragma unroll
            for (int ks = 0; ks < 4; ++ks)
                acc = __builtin_amdgcn_mfma_f32_16x16x32_bf16(a[ks], w1f[ks][nb], acc, 0, 0, 0);
#pragma unroll
            for (int r = 0; r < 4; ++r) {
                float hv = fmaxf(acc[r] + b1v[nb], 0.f);
                Hw[(quad * 4 + r) * 72 + nb * 16 + mr] = __float2bfloat16(hv);
            }
        }

        bf16x8 h[2];
#pragma unroll
        for (int ks = 0; ks < 2; ++ks)
            h[ks] = *(const bf16x8*)&Hw[mr * 72 + ks * 32 + quad * 8];

#pragma unroll
        for (int nb = 0; nb < 4; ++nb) {
            f32x4 acc = {0.f, 0.f, 0.f, 0.f};
            acc = __builtin_amdgcn_mfma_f32_16x16x32_bf16(h[0], w2f[0][nb], acc, 0, 0, 0);
            acc = __builtin_amdgcn_mfma_f32_16x16x32_bf16(h[1], w2f[1][nb], acc, 0, 0, 0);
#pragma unroll
            for (int r = 0; r < 4; ++r) {
                int vrow = v0 + quad * 4 + r;
                if (vrow < n_nodes)
                    out[(size_t)vrow * D + nb * 16 + mr] = acc[r] + b2v[nb];
            }
        }
    }
}

// ---------------------------------------------------------------------------
extern "C" void kernel_launch(void* const* d_in, const int* in_sizes, int n_in,
                              void* d_out, int out_size, void* d_ws, size_t ws_size,
                              hipStream_t stream) {
    const float* x   = (const float*)d_in[0];
    const int*   ei  = (const int*)d_in[1];
    // d_in[2] = batch (unused)
    const float* mw1 = (const float*)d_in[3];
    const float* mb1 = (const float*)d_in[4];
    const float* mw2 = (const float*)d_in[5];
    const float* mb2 = (const float*)d_in[6];
    const float* ow1 = (const float*)d_in[7];
    const float* ob1 = (const float*)d_in[8];
    const float* ow2 = (const float*)d_in[9];
    const float* ob2 = (const float*)d_in[10];

    const int n_nodes = in_sizes[0] / D;        // 100000
    const int n_edges = in_sizes[1] / 2;        // 1000000
    const int* row = ei;                        // edge_index[0]
    const int* col = ei + n_edges;              // edge_index[1]

    const int nbuckets = (n_nodes + BW - 1) >> BSHIFT;   // 782

    // ws layout
    __hip_bfloat16* m = (__hip_bfloat16*)d_ws;            // [n_nodes*64] bf16
    float* agg = (float*)(m + (size_t)n_nodes * D);       // [n_nodes*64] f32
    unsigned int* tmp = (unsigned int*)(agg + (size_t)n_nodes * D); // [n_edges]
    int* bcount = (int*)(tmp + n_edges);                  // [nbuckets]
    int* gstart = bcount + nbuckets;                      // [nbuckets]
    int* gcur   = gstart + nbuckets;                      // [nbuckets]
    const size_t need = (size_t)n_nodes * D * 6 + (size_t)n_edges * 4
                      + (size_t)nbuckets * 12;

    const int ntiles = (n_nodes + 15) / 16;
    const int nblk   = (ntiles + 3) / 4;

    msg_kernel<<<nblk, 256, 0, stream>>>(x, mw1, mb1, mw2, mb2, m, n_nodes);

    const bool shape_ok = (n_nodes < (1 << 17)) && (nbuckets <= MAXB);

    if (ws_size >= need && shape_ok) {
        hipMemsetAsync(bcount, 0, (size_t)nbuckets * sizeof(int), stream);
        bhist_kernel<<<256, 256, 0, stream>>>(col, bcount, n_edges, nbuckets);
        bscan_kernel<<<1, 1024, 0, stream>>>(bcount, gstart, gcur, nbuckets);
        const int nbbin = 256;
        const int chunk = (n_edges + nbbin - 1) / nbbin;
        bin_kernel<<<nbbin, 256, 0, stream>>>(row, col, gcur, tmp,
                                              n_edges, nbuckets, chunk);
        bucket_gather_kernel<<<nbuckets, 256, 0, stream>>>(gstart, tmp, m, agg,
                                                           n_nodes, n_edges, nbuckets);
    } else {
        hipMemsetAsync(agg, 0, (size_t)n_nodes * D * sizeof(float), stream);
        const int nwaves_s = (n_edges + 63) / 64;
        scatter_kernel<<<(nwaves_s + 3) / 4, 256, 0, stream>>>(row, col, m, agg, n_edges);
    }

    out_kernel<<<nblk, 256, 0, stream>>>(x, agg, ow1, ob1, ow2, ob2,
                                         (float*)d_out, n_nodes);
}

// Round 10
// 594.504 us; speedup vs baseline: 1.0153x; 1.0048x over previous
//
#include <hip/hip_runtime.h>
#include <hip/hip_bf16.h>

#define D 64
#define BSHIFT 7
#define BW (1 << BSHIFT)          // bucket width: 128 destination nodes (32 KB tile)
#define MAXB 1024                 // max buckets (bscan is a 1024-thread scan)

typedef __attribute__((ext_vector_type(8))) short bf16x8;   // 8 bf16 in 4 VGPRs
typedef __attribute__((ext_vector_type(4))) float f32x4;

__device__ __forceinline__ short f2bf(float f) {
    __hip_bfloat16 h = __float2bfloat16(f);
    return *reinterpret_cast<short*>(&h);
}

// ---------------------------------------------------------------------------
// K1: per-node message MLP via MFMA.  m[v] = relu(x[v]@W1 + b1)@W2 + b2
// Output m stored as bf16 (halves downstream random-read bytes).
// ---------------------------------------------------------------------------
__global__ __launch_bounds__(256) void msg_kernel(
    const float* __restrict__ x,
    const float* __restrict__ w1, const float* __restrict__ b1,
    const float* __restrict__ w2, const float* __restrict__ b2,
    __hip_bfloat16* __restrict__ m, int n_nodes)
{
    __shared__ __align__(16) __hip_bfloat16 sH[4][16 * 72];

    const int lane = threadIdx.x & 63;
    const int wslot = threadIdx.x >> 6;
    const int mr   = lane & 15;
    const int quad = lane >> 4;

    bf16x8 w1f[2][4], w2f[2][4];
    float  b1v[4], b2v[4];
#pragma unroll
    for (int ks = 0; ks < 2; ++ks)
#pragma unroll
        for (int nb = 0; nb < 4; ++nb) {
            bf16x8 f1, f2;
#pragma unroll
            for (int j = 0; j < 8; ++j) {
                int k = ks * 32 + quad * 8 + j;
                f1[j] = f2bf(w1[k * D + nb * 16 + mr]);
                f2[j] = f2bf(w2[k * D + nb * 16 + mr]);
            }
            w1f[ks][nb] = f1;
            w2f[ks][nb] = f2;
        }
#pragma unroll
    for (int nb = 0; nb < 4; ++nb) {
        b1v[nb] = b1[nb * 16 + mr];
        b2v[nb] = b2[nb * 16 + mr];
    }

    __hip_bfloat16* Hw = sH[wslot];
    const int wid    = (blockIdx.x * blockDim.x + threadIdx.x) >> 6;
    const int nwaves = (gridDim.x * blockDim.x) >> 6;
    const int ntiles = (n_nodes + 15) >> 4;

    for (int t = wid; t < ntiles; t += nwaves) {
        const int v0 = t * 16;
        int vr = v0 + mr;
        if (vr >= n_nodes) vr = n_nodes - 1;

        bf16x8 a[2];
#pragma unroll
        for (int ks = 0; ks < 2; ++ks) {
            const float* p = x + (size_t)vr * D + ks * 32 + quad * 8;
            float4 lo = *(const float4*)p;
            float4 hi = *(const float4*)(p + 4);
            bf16x8 f;
            f[0] = f2bf(lo.x); f[1] = f2bf(lo.y); f[2] = f2bf(lo.z); f[3] = f2bf(lo.w);
            f[4] = f2bf(hi.x); f[5] = f2bf(hi.y); f[6] = f2bf(hi.z); f[7] = f2bf(hi.w);
            a[ks] = f;
        }

#pragma unroll
        for (int nb = 0; nb < 4; ++nb) {
            f32x4 acc = {0.f, 0.f, 0.f, 0.f};
            acc = __builtin_amdgcn_mfma_f32_16x16x32_bf16(a[0], w1f[0][nb], acc, 0, 0, 0);
            acc = __builtin_amdgcn_mfma_f32_16x16x32_bf16(a[1], w1f[1][nb], acc, 0, 0, 0);
#pragma unroll
            for (int r = 0; r < 4; ++r) {
                float hv = fmaxf(acc[r] + b1v[nb], 0.f);
                Hw[(quad * 4 + r) * 72 + nb * 16 + mr] = __float2bfloat16(hv);
            }
        }

        bf16x8 h[2];
#pragma unroll
        for (int ks = 0; ks < 2; ++ks)
            h[ks] = *(const bf16x8*)&Hw[mr * 72 + ks * 32 + quad * 8];

#pragma unroll
        for (int nb = 0; nb < 4; ++nb) {
            f32x4 acc = {0.f, 0.f, 0.f, 0.f};
            acc = __builtin_amdgcn_mfma_f32_16x16x32_bf16(h[0], w2f[0][nb], acc, 0, 0, 0);
            acc = __builtin_amdgcn_mfma_f32_16x16x32_bf16(h[1], w2f[1][nb], acc, 0, 0, 0);
#pragma unroll
            for (int r = 0; r < 4; ++r) {
                int vrow = v0 + quad * 4 + r;
                if (vrow < n_nodes)
                    m[(size_t)vrow * D + nb * 16 + mr] =
                        __float2bfloat16(acc[r] + b2v[nb]);
            }
        }
    }
}

// ---------------------------------------------------------------------------
// Bucket-level CSR: bhist -> bscan -> bin (packed (c_local<<17)|src per bucket).
// ---------------------------------------------------------------------------
__global__ __launch_bounds__(256) void bhist_kernel(
    const int* __restrict__ col, int* __restrict__ bcount,
    int n_edges, int nbuckets)
{
    __shared__ int h[MAXB];
    for (int i = threadIdx.x; i < nbuckets; i += 256) h[i] = 0;
    __syncthreads();
    for (int e = blockIdx.x * blockDim.x + threadIdx.x; e < n_edges;
         e += gridDim.x * blockDim.x)
        atomicAdd(&h[col[e] >> BSHIFT], 1);
    __syncthreads();
    for (int i = threadIdx.x; i < nbuckets; i += 256)
        if (h[i]) atomicAdd(&bcount[i], h[i]);
}

// 1 block: exclusive scan of bcount -> gstart (kept) and gcur (consumed by bin).
__global__ __launch_bounds__(1024) void bscan_kernel(
    const int* __restrict__ bcount, int* __restrict__ gstart,
    int* __restrict__ gcur, int nbuckets)
{
    __shared__ int tmp[1024];
    const int t = threadIdx.x;
    int v = (t < nbuckets) ? bcount[t] : 0;
    tmp[t] = v;
    __syncthreads();
    for (int off = 1; off < 1024; off <<= 1) {
        int u = (t >= off) ? tmp[t - off] : 0;
        __syncthreads();
        tmp[t] += u;
        __syncthreads();
    }
    if (t < nbuckets) {
        int e = tmp[t] - v;   // exclusive
        gstart[t] = e;
        gcur[t]   = e;
    }
}

// Bin edges by destination bucket into packed u32: (c_local<<17) | src.
__global__ __launch_bounds__(256) void bin_kernel(
    const int* __restrict__ row, const int* __restrict__ col,
    int* __restrict__ gcur, unsigned int* __restrict__ tmp,
    int n_edges, int nbuckets, int chunk)
{
    __shared__ int hist[MAXB], base[MAXB], lcur[MAXB];
    const int t = threadIdx.x;
    const int e0 = blockIdx.x * chunk;
    const int e1 = min(e0 + chunk, n_edges);

    for (int i = t; i < nbuckets; i += 256) hist[i] = 0;
    __syncthreads();
    for (int e = e0 + t; e < e1; e += 256)
        atomicAdd(&hist[col[e] >> BSHIFT], 1);
    __syncthreads();
    for (int i = t; i < nbuckets; i += 256) {
        base[i] = hist[i] ? atomicAdd(&gcur[i], hist[i]) : 0;
        lcur[i] = 0;
    }
    __syncthreads();
    for (int e = e0 + t; e < e1; e += 256) {
        int c = col[e];
        int b = c >> BSHIFT;
        int loc = atomicAdd(&lcur[b], 1);
        unsigned int val = ((unsigned int)(c & (BW - 1)) << 17)
                         | (unsigned int)row[e];
        tmp[base[b] + loc] = val;
    }
}

// ---------------------------------------------------------------------------
// K2: fused fill+gather.  One 1024-thread block (16 waves) per 128-node
// bucket; 32 KB fp32 tile in LDS (2 blocks/CU -> 32 waves/CU, 100% occ
// ceiling). Per wave only ~1-2 chunks of 64 edges (short-lived, R6-style TLP)
// with 8-deep ILP on the random bf16 m-row loads -> up to 256 outstanding
// loads/CU. LDS atomic accumulate (lane->bank 2-way = free), coalesced
// float4 writeback.
// ---------------------------------------------------------------------------
__global__ __launch_bounds__(1024) void bucket_gather_kernel(
    const int* __restrict__ gstart, const unsigned int* __restrict__ tmp,
    const __hip_bfloat16* __restrict__ m, float* __restrict__ agg,
    int n_nodes, int n_edges, int nbuckets)
{
    __shared__ __align__(16) float tile[BW * D];   // 32 KB

    const int b     = blockIdx.x;
    const int lane  = threadIdx.x & 63;
    const int wv    = threadIdx.x >> 6;            // 0..15
    const int vbase = b << BSHIFT;
    const int nloc  = min(BW, n_nodes - vbase);

    float4* t4 = (float4*)tile;
    for (int i = threadIdx.x; i < BW * D / 4; i += 1024)
        t4[i] = make_float4(0.f, 0.f, 0.f, 0.f);
    __syncthreads();

    const int start = gstart[b];
    const int end   = (b + 1 < nbuckets) ? gstart[b + 1] : n_edges;

    for (int cs = start + wv * 64; cs < end; cs += 1024) {
        const int cnt = min(64, end - cs);
        unsigned int pv = 0;
        if (lane < cnt) pv = tmp[cs + lane];

        int j = 0;
        for (; j + 8 <= cnt; j += 8) {
            unsigned int u[8];
            float v[8];
#pragma unroll
            for (int q = 0; q < 8; ++q)
                u[q] = __builtin_amdgcn_readlane(pv, j + q);
#pragma unroll
            for (int q = 0; q < 8; ++q)
                v[q] = (float)m[(size_t)(u[q] & 0x1FFFFu) * D + lane];
#pragma unroll
            for (int q = 0; q < 8; ++q)
                atomicAdd(&tile[(u[q] >> 17) * D + lane], v[q]);
        }
        for (; j < cnt; ++j) {
            unsigned int u = __builtin_amdgcn_readlane(pv, j);
            float v = (float)m[(size_t)(u & 0x1FFFFu) * D + lane];
            atomicAdd(&tile[(u >> 17) * D + lane], v);
        }
    }
    __syncthreads();

    float4* a4 = (float4*)(agg + (size_t)vbase * D);
    for (int i = threadIdx.x; i < nloc * D / 4; i += 1024)
        a4[i] = t4[i];
}

// ---------------------------------------------------------------------------
// Fallback scatter (ws too small / shape out of range): fp32 atomics.
// ---------------------------------------------------------------------------
__global__ __launch_bounds__(256) void scatter_kernel(
    const int* __restrict__ row, const int* __restrict__ col,
    const __hip_bfloat16* __restrict__ m, float* __restrict__ agg, int n_edges)
{
    const int lane = threadIdx.x & 63;
    const int wid  = (blockIdx.x * blockDim.x + threadIdx.x) >> 6;
    const int base = wid * 64;
    if (base >= n_edges) return;
    const int cnt = min(64, n_edges - base);

    int my_r = 0, my_c = 0;
    if (lane < cnt) { my_r = row[base + lane]; my_c = col[base + lane]; }

    for (int j = 0; j < cnt; ++j) {
        int r = __builtin_amdgcn_readlane(my_r, j);
        int c = __builtin_amdgcn_readlane(my_c, j);
        float v = (float)m[(size_t)r * D + lane];
        atomicAdd(&agg[(size_t)c * D + lane], v);
    }
}

// ---------------------------------------------------------------------------
// K3: output MLP via MFMA.  out[v] = relu([x[v],agg[v]]@OW1 + ob1)@OW2 + ob2
// ---------------------------------------------------------------------------
__global__ __launch_bounds__(256) void out_kernel(
    const float* __restrict__ x, const float* __restrict__ agg,
    const float* __restrict__ w1, const float* __restrict__ b1,
    const float* __restrict__ w2, const float* __restrict__ b2,
    float* __restrict__ out, int n_nodes)
{
    __shared__ __align__(16) __hip_bfloat16 sH[4][16 * 72];

    const int lane = threadIdx.x & 63;
    const int wslot = threadIdx.x >> 6;
    const int mr   = lane & 15;
    const int quad = lane >> 4;

    bf16x8 w1f[4][4], w2f[2][4];
    float  b1v[4], b2v[4];
#pragma unroll
    for (int ks = 0; ks < 4; ++ks)
#pragma unroll
        for (int nb = 0; nb < 4; ++nb) {
            bf16x8 f;
#pragma unroll
            for (int j = 0; j < 8; ++j) {
                int k = ks * 32 + quad * 8 + j;
                f[j] = f2bf(w1[k * D + nb * 16 + mr]);
            }
            w1f[ks][nb] = f;
        }
#pragma unroll
    for (int ks = 0; ks < 2; ++ks)
#pragma unroll
        for (int nb = 0; nb < 4; ++nb) {
            bf16x8 f;
#pragma unroll
            for (int j = 0; j < 8; ++j) {
                int k = ks * 32 + quad * 8 + j;
                f[j] = f2bf(w2[k * D + nb * 16 + mr]);
            }
            w2f[ks][nb] = f;
        }
#pragma unroll
    for (int nb = 0; nb < 4; ++nb) {
        b1v[nb] = b1[nb * 16 + mr];
        b2v[nb] = b2[nb * 16 + mr];
    }

    __hip_bfloat16* Hw = sH[wslot];
    const int wid    = (blockIdx.x * blockDim.x + threadIdx.x) >> 6;
    const int nwaves = (gridDim.x * blockDim.x) >> 6;
    const int ntiles = (n_nodes + 15) >> 4;

    for (int t = wid; t < ntiles; t += nwaves) {
        const int v0 = t * 16;
        int vr = v0 + mr;
        if (vr >= n_nodes) vr = n_nodes - 1;

        bf16x8 a[4];
#pragma unroll
        for (int ks = 0; ks < 4; ++ks) {
            const float* src = (ks < 2) ? (x + (size_t)vr * D + ks * 32)
                                        : (agg + (size_t)vr * D + (ks - 2) * 32);
            const float* p = src + quad * 8;
            float4 lo = *(const float4*)p;
            float4 hi = *(const float4*)(p + 4);
            bf16x8 f;
            f[0] = f2bf(lo.x); f[1] = f2bf(lo.y); f[2] = f2bf(lo.z); f[3] = f2bf(lo.w);
            f[4] = f2bf(hi.x); f[5] = f2bf(hi.y); f[6] = f2bf(hi.z); f[7] = f2bf(hi.w);
            a[ks] = f;
        }

#pragma unroll
        for (int nb = 0; nb < 4; ++nb) {
            f32x4 acc = {0.f, 0.f, 0.f, 0.f};
#pragma unroll
            for (int ks = 0; ks < 4; ++ks)
                acc = __builtin_amdgcn_mfma_f32_16x16x32_bf16(a[ks], w1f[ks][nb], acc, 0, 0, 0);
#pragma unroll
            for (int r = 0; r < 4; ++r) {
                float hv = fmaxf(acc[r] + b1v[nb], 0.f);
                Hw[(quad * 4 + r) * 72 + nb * 16 + mr] = __float2bfloat16(hv);
            }
        }

        bf16x8 h[2];
#pragma unroll
        for (int ks = 0; ks < 2; ++ks)
            h[ks] = *(const bf16x8*)&Hw[mr * 72 + ks * 32 + quad * 8];

#pragma unroll
        for (int nb = 0; nb < 4; ++nb) {
            f32x4 acc = {0.f, 0.f, 0.f, 0.f};
            acc = __builtin_amdgcn_mfma_f32_16x16x32_bf16(h[0], w2f[0][nb], acc, 0, 0, 0);
            acc = __builtin_amdgcn_mfma_f32_16x16x32_bf16(h[1], w2f[1][nb], acc, 0, 0, 0);
#pragma unroll
            for (int r = 0; r < 4; ++r) {
                int vrow = v0 + quad * 4 + r;
                if (vrow < n_nodes)
                    out[(size_t)vrow * D + nb * 16 + mr] = acc[r] + b2v[nb];
            }
        }
    }
}

// ---------------------------------------------------------------------------
extern "C" void kernel_launch(void* const* d_in, const int* in_sizes, int n_in,
                              void* d_out, int out_size, void* d_ws, size_t ws_size,
                              hipStream_t stream) {
    const float* x   = (const float*)d_in[0];
    const int*   ei  = (const int*)d_in[1];
    // d_in[2] = batch (unused)
    const float* mw1 = (const float*)d_in[3];
    const float* mb1 = (const float*)d_in[4];
    const float* mw2 = (const float*)d_in[5];
    const float* mb2 = (const float*)d_in[6];
    const float* ow1 = (const float*)d_in[7];
    const float* ob1 = (const float*)d_in[8];
    const float* ow2 = (const float*)d_in[9];
    const float* ob2 = (const float*)d_in[10];

    const int n_nodes = in_sizes[0] / D;        // 100000
    const int n_edges = in_sizes[1] / 2;        // 1000000
    const int* row = ei;                        // edge_index[0]
    const int* col = ei + n_edges;              // edge_index[1]

    const int nbuckets = (n_nodes + BW - 1) >> BSHIFT;   // 782

    // ws layout
    __hip_bfloat16* m = (__hip_bfloat16*)d_ws;            // [n_nodes*64] bf16
    float* agg = (float*)(m + (size_t)n_nodes * D);       // [n_nodes*64] f32
    unsigned int* tmp = (unsigned int*)(agg + (size_t)n_nodes * D); // [n_edges]
    int* bcount = (int*)(tmp + n_edges);                  // [nbuckets]
    int* gstart = bcount + nbuckets;                      // [nbuckets]
    int* gcur   = gstart + nbuckets;                      // [nbuckets]
    const size_t need = (size_t)n_nodes * D * 6 + (size_t)n_edges * 4
                      + (size_t)nbuckets * 12;

    const int ntiles = (n_nodes + 15) / 16;
    const int nblk   = (ntiles + 3) / 4;

    msg_kernel<<<nblk, 256, 0, stream>>>(x, mw1, mb1, mw2, mb2, m, n_nodes);

    const bool shape_ok = (n_nodes < (1 << 17)) && (nbuckets <= MAXB);

    if (ws_size >= need && shape_ok) {
        hipMemsetAsync(bcount, 0, (size_t)nbuckets * sizeof(int), stream);
        bhist_kernel<<<256, 256, 0, stream>>>(col, bcount, n_edges, nbuckets);
        bscan_kernel<<<1, 1024, 0, stream>>>(bcount, gstart, gcur, nbuckets);
        const int nbbin = 128;
        const int chunk = (n_edges + nbbin - 1) / nbbin;
        bin_kernel<<<nbbin, 256, 0, stream>>>(row, col, gcur, tmp,
                                              n_edges, nbuckets, chunk);
        bucket_gather_kernel<<<nbuckets, 1024, 0, stream>>>(gstart, tmp, m, agg,
                                                            n_nodes, n_edges, nbuckets);
    } else {
        hipMemsetAsync(agg, 0, (size_t)n_nodes * D * sizeof(float), stream);
        const int nwaves_s = (n_edges + 63) / 64;
        scatter_kernel<<<(nwaves_s + 3) / 4, 256, 0, stream>>>(row, col, m, agg, n_edges);
    }

    out_kernel<<<nblk, 256, 0, stream>>>(x, agg, ow1, ob1, ow2, ob2,
                                         (float*)d_out, n_nodes);
}

// Round 11
// 224.984 us; speedup vs baseline: 2.6828x; 2.6424x over previous
//
#include <hip/hip_runtime.h>
#include <hip/hip_bf16.h>

#define D 64
#define BSHIFT 7
#define BW (1 << BSHIFT)          // bucket width: 128 destination nodes
#define MAXB 1024                 // max buckets (bscan is a 1024-thread scan)
#define CAP 8192                  // max edges sorted per LDS round (32 KB)

typedef __attribute__((ext_vector_type(8))) short bf16x8;   // 8 bf16 in 4 VGPRs
typedef __attribute__((ext_vector_type(4))) float f32x4;

__device__ __forceinline__ short f2bf(float f) {
    __hip_bfloat16 h = __float2bfloat16(f);
    return *reinterpret_cast<short*>(&h);
}

// ---------------------------------------------------------------------------
// K1: per-node message MLP via MFMA.  m[v] = relu(x[v]@W1 + b1)@W2 + b2
// ---------------------------------------------------------------------------
__global__ __launch_bounds__(256) void msg_kernel(
    const float* __restrict__ x,
    const float* __restrict__ w1, const float* __restrict__ b1,
    const float* __restrict__ w2, const float* __restrict__ b2,
    float* __restrict__ m, int n_nodes)
{
    __shared__ __align__(16) __hip_bfloat16 sH[4][16 * 72];

    const int lane = threadIdx.x & 63;
    const int wslot = threadIdx.x >> 6;
    const int mr   = lane & 15;
    const int quad = lane >> 4;

    bf16x8 w1f[2][4], w2f[2][4];
    float  b1v[4], b2v[4];
#pragma unroll
    for (int ks = 0; ks < 2; ++ks)
#pragma unroll
        for (int nb = 0; nb < 4; ++nb) {
            bf16x8 f1, f2;
#pragma unroll
            for (int j = 0; j < 8; ++j) {
                int k = ks * 32 + quad * 8 + j;
                f1[j] = f2bf(w1[k * D + nb * 16 + mr]);
                f2[j] = f2bf(w2[k * D + nb * 16 + mr]);
            }
            w1f[ks][nb] = f1;
            w2f[ks][nb] = f2;
        }
#pragma unroll
    for (int nb = 0; nb < 4; ++nb) {
        b1v[nb] = b1[nb * 16 + mr];
        b2v[nb] = b2[nb * 16 + mr];
    }

    __hip_bfloat16* Hw = sH[wslot];
    const int wid    = (blockIdx.x * blockDim.x + threadIdx.x) >> 6;
    const int nwaves = (gridDim.x * blockDim.x) >> 6;
    const int ntiles = (n_nodes + 15) >> 4;

    for (int t = wid; t < ntiles; t += nwaves) {
        const int v0 = t * 16;
        int vr = v0 + mr;
        if (vr >= n_nodes) vr = n_nodes - 1;

        bf16x8 a[2];
#pragma unroll
        for (int ks = 0; ks < 2; ++ks) {
            const float* p = x + (size_t)vr * D + ks * 32 + quad * 8;
            float4 lo = *(const float4*)p;
            float4 hi = *(const float4*)(p + 4);
            bf16x8 f;
            f[0] = f2bf(lo.x); f[1] = f2bf(lo.y); f[2] = f2bf(lo.z); f[3] = f2bf(lo.w);
            f[4] = f2bf(hi.x); f[5] = f2bf(hi.y); f[6] = f2bf(hi.z); f[7] = f2bf(hi.w);
            a[ks] = f;
        }

#pragma unroll
        for (int nb = 0; nb < 4; ++nb) {
            f32x4 acc = {0.f, 0.f, 0.f, 0.f};
            acc = __builtin_amdgcn_mfma_f32_16x16x32_bf16(a[0], w1f[0][nb], acc, 0, 0, 0);
            acc = __builtin_amdgcn_mfma_f32_16x16x32_bf16(a[1], w1f[1][nb], acc, 0, 0, 0);
#pragma unroll
            for (int r = 0; r < 4; ++r) {
                float hv = fmaxf(acc[r] + b1v[nb], 0.f);
                Hw[(quad * 4 + r) * 72 + nb * 16 + mr] = __float2bfloat16(hv);
            }
        }

        bf16x8 h[2];
#pragma unroll
        for (int ks = 0; ks < 2; ++ks)
            h[ks] = *(const bf16x8*)&Hw[mr * 72 + ks * 32 + quad * 8];

#pragma unroll
        for (int nb = 0; nb < 4; ++nb) {
            f32x4 acc = {0.f, 0.f, 0.f, 0.f};
            acc = __builtin_amdgcn_mfma_f32_16x16x32_bf16(h[0], w2f[0][nb], acc, 0, 0, 0);
            acc = __builtin_amdgcn_mfma_f32_16x16x32_bf16(h[1], w2f[1][nb], acc, 0, 0, 0);
#pragma unroll
            for (int r = 0; r < 4; ++r) {
                int vrow = v0 + quad * 4 + r;
                if (vrow < n_nodes)
                    m[(size_t)vrow * D + nb * 16 + mr] = acc[r] + b2v[nb];
            }
        }
    }
}

// ---------------------------------------------------------------------------
// Bucket-level CSR: bhist -> bscan -> bin (packed (c_local<<17)|src per bucket).
// ---------------------------------------------------------------------------
__global__ __launch_bounds__(256) void bhist_kernel(
    const int* __restrict__ col, int* __restrict__ bcount,
    int n_edges, int nbuckets)
{
    __shared__ int h[MAXB];
    for (int i = threadIdx.x; i < nbuckets; i += 256) h[i] = 0;
    __syncthreads();
    for (int e = blockIdx.x * blockDim.x + threadIdx.x; e < n_edges;
         e += gridDim.x * blockDim.x)
        atomicAdd(&h[col[e] >> BSHIFT], 1);
    __syncthreads();
    for (int i = threadIdx.x; i < nbuckets; i += 256)
        if (h[i]) atomicAdd(&bcount[i], h[i]);
}

// 1 block: exclusive scan of bcount -> gstart (kept) and gcur (consumed by bin).
__global__ __launch_bounds__(1024) void bscan_kernel(
    const int* __restrict__ bcount, int* __restrict__ gstart,
    int* __restrict__ gcur, int nbuckets)
{
    __shared__ int tmp[1024];
    const int t = threadIdx.x;
    int v = (t < nbuckets) ? bcount[t] : 0;
    tmp[t] = v;
    __syncthreads();
    for (int off = 1; off < 1024; off <<= 1) {
        int u = (t >= off) ? tmp[t - off] : 0;
        __syncthreads();
        tmp[t] += u;
        __syncthreads();
    }
    if (t < nbuckets) {
        int e = tmp[t] - v;   // exclusive
        gstart[t] = e;
        gcur[t]   = e;
    }
}

// Bin edges by destination bucket into packed u32: (c_local<<17) | src.
__global__ __launch_bounds__(256) void bin_kernel(
    const int* __restrict__ row, const int* __restrict__ col,
    int* __restrict__ gcur, unsigned int* __restrict__ tmp,
    int n_edges, int nbuckets, int chunk)
{
    __shared__ int hist[MAXB], base[MAXB], lcur[MAXB];
    const int t = threadIdx.x;
    const int e0 = blockIdx.x * chunk;
    const int e1 = min(e0 + chunk, n_edges);

    for (int i = t; i < nbuckets; i += 256) hist[i] = 0;
    __syncthreads();
    for (int e = e0 + t; e < e1; e += 256)
        atomicAdd(&hist[col[e] >> BSHIFT], 1);
    __syncthreads();
    for (int i = t; i < nbuckets; i += 256) {
        base[i] = hist[i] ? atomicAdd(&gcur[i], hist[i]) : 0;
        lcur[i] = 0;
    }
    __syncthreads();
    for (int e = e0 + t; e < e1; e += 256) {
        int c = col[e];
        int b = c >> BSHIFT;
        int loc = atomicAdd(&lcur[b], 1);
        unsigned int val = ((unsigned int)(c & (BW - 1)) << 17)
                         | (unsigned int)row[e];
        tmp[base[b] + loc] = val;
    }
}

// ---------------------------------------------------------------------------
// K2: fused in-LDS CSR sort + register gather.  One 1024-thread block per
// 128-node bucket.  Per round: int LDS histogram (native ds_add) -> 7-step
// parallel scan -> scatter packed entries to a sorted LDS array (32 KB).
// Then each wave owns 8 nodes, streams their srcs from LDS via readlane,
// 8-deep ILP fp32 m-row loads, REGISTER accumulation (no float atomics
// anywhere -- R7-R9's 430us was the per-edge LDS float RMW chain).
// Single coalesced agg write per node.
// ---------------------------------------------------------------------------
__global__ __launch_bounds__(1024) void bucket_gather_kernel(
    const int* __restrict__ gstart, const unsigned int* __restrict__ tmp,
    const float* __restrict__ m, float* __restrict__ agg,
    int n_nodes, int n_edges, int nbuckets)
{
    __shared__ unsigned int sorted[CAP];   // 32 KB
    __shared__ int cnt[BW], off[BW], cur[BW];

    const int b    = blockIdx.x;
    const int t    = threadIdx.x;
    const int lane = t & 63;
    const int wv   = t >> 6;               // 0..15
    const int vbase = b << BSHIFT;

    const int start = gstart[b];
    const int end   = (b + 1 < nbuckets) ? gstart[b + 1] : n_edges;

    float acc[8];                          // wave wv owns nodes wv + 16*i
#pragma unroll
    for (int i = 0; i < 8; ++i) acc[i] = 0.f;

    for (int r0 = start; r0 < end; r0 += CAP) {
        const int r1 = min(r0 + CAP, end);

        if (t < BW) cnt[t] = 0;
        __syncthreads();

        // histogram (int LDS atomics: native ds_add)
        for (int i = r0 + t; i < r1; i += 1024)
            atomicAdd(&cnt[tmp[i] >> 17], 1);
        __syncthreads();

        // exclusive scan of cnt -> off, cur
        if (t < BW) off[t] = cnt[t];
        __syncthreads();
        for (int d = 1; d < BW; d <<= 1) {
            int u = 0;
            if (t < BW && t >= d) u = off[t - d];
            __syncthreads();
            if (t < BW) off[t] += u;
            __syncthreads();
        }
        if (t < BW) {
            int e = off[t] - cnt[t];
            off[t] = e;
            cur[t] = e;
        }
        __syncthreads();

        // scatter to sorted order (int LDS atomics + plain LDS writes)
        for (int i = r0 + t; i < r1; i += 1024) {
            unsigned int u = tmp[i];
            int pos = atomicAdd(&cur[u >> 17], 1);
            sorted[pos] = u;
        }
        __syncthreads();

        // register gather: 8 nodes per wave
#pragma unroll
        for (int i = 0; i < 8; ++i) {
            const int n  = wv + (i << 4);
            const int o0 = off[n];
            const int c  = cnt[n];
            float s = 0.f;
            for (int cs = 0; cs < c; cs += 64) {
                const int k = min(64, c - cs);
                unsigned int pv = 0;
                if (lane < k) pv = sorted[o0 + cs + lane];

                int j = 0;
                for (; j + 8 <= k; j += 8) {
                    unsigned int u[8];
                    float v[8];
#pragma unroll
                    for (int q = 0; q < 8; ++q)
                        u[q] = __builtin_amdgcn_readlane(pv, j + q);
#pragma unroll
                    for (int q = 0; q < 8; ++q)
                        v[q] = m[(size_t)(u[q] & 0x1FFFFu) * D + lane];
#pragma unroll
                    for (int q = 0; q < 8; ++q)
                        s += v[q];
                }
                for (; j < k; ++j) {
                    unsigned int u = __builtin_amdgcn_readlane(pv, j);
                    s += m[(size_t)(u & 0x1FFFFu) * D + lane];
                }
            }
            acc[i] += s;
        }
        __syncthreads();   // protect cnt/off/sorted for next round
    }

    // coalesced writeback
#pragma unroll
    for (int i = 0; i < 8; ++i) {
        const int v = vbase + wv + (i << 4);
        if (v < n_nodes)
            agg[(size_t)v * D + lane] = acc[i];
    }
}

// ---------------------------------------------------------------------------
// Fallback scatter (ws too small / shape out of range): fp32 atomics.
// ---------------------------------------------------------------------------
__global__ __launch_bounds__(256) void scatter_kernel(
    const int* __restrict__ row, const int* __restrict__ col,
    const float* __restrict__ m, float* __restrict__ agg, int n_edges)
{
    const int lane = threadIdx.x & 63;
    const int wid  = (blockIdx.x * blockDim.x + threadIdx.x) >> 6;
    const int base = wid * 64;
    if (base >= n_edges) return;
    const int cnt = min(64, n_edges - base);

    int my_r = 0, my_c = 0;
    if (lane < cnt) { my_r = row[base + lane]; my_c = col[base + lane]; }

    for (int j = 0; j < cnt; ++j) {
        int r = __builtin_amdgcn_readlane(my_r, j);
        int c = __builtin_amdgcn_readlane(my_c, j);
        float v = m[(size_t)r * D + lane];
        atomicAdd(&agg[(size_t)c * D + lane], v);
    }
}

// ---------------------------------------------------------------------------
// K3: output MLP via MFMA.  out[v] = relu([x[v],agg[v]]@OW1 + ob1)@OW2 + ob2
// ---------------------------------------------------------------------------
__global__ __launch_bounds__(256) void out_kernel(
    const float* __restrict__ x, const float* __restrict__ agg,
    const float* __restrict__ w1, const float* __restrict__ b1,
    const float* __restrict__ w2, const float* __restrict__ b2,
    float* __restrict__ out, int n_nodes)
{
    __shared__ __align__(16) __hip_bfloat16 sH[4][16 * 72];

    const int lane = threadIdx.x & 63;
    const int wslot = threadIdx.x >> 6;
    const int mr   = lane & 15;
    const int quad = lane >> 4;

    bf16x8 w1f[4][4], w2f[2][4];
    float  b1v[4], b2v[4];
#pragma unroll
    for (int ks = 0; ks < 4; ++ks)
#pragma unroll
        for (int nb = 0; nb < 4; ++nb) {
            bf16x8 f;
#pragma unroll
            for (int j = 0; j < 8; ++j) {
                int k = ks * 32 + quad * 8 + j;
                f[j] = f2bf(w1[k * D + nb * 16 + mr]);
            }
            w1f[ks][nb] = f;
        }
#pragma unroll
    for (int ks = 0; ks < 2; ++ks)
#pragma unroll
        for (int nb = 0; nb < 4; ++nb) {
            bf16x8 f;
#pragma unroll
            for (int j = 0; j < 8; ++j) {
                int k = ks * 32 + quad * 8 + j;
                f[j] = f2bf(w2[k * D + nb * 16 + mr]);
            }
            w2f[ks][nb] = f;
        }
#pragma unroll
    for (int nb = 0; nb < 4; ++nb) {
        b1v[nb] = b1[nb * 16 + mr];
        b2v[nb] = b2[nb * 16 + mr];
    }

    __hip_bfloat16* Hw = sH[wslot];
    const int wid    = (blockIdx.x * blockDim.x + threadIdx.x) >> 6;
    const int nwaves = (gridDim.x * blockDim.x) >> 6;
    const int ntiles = (n_nodes + 15) >> 4;

    for (int t = wid; t < ntiles; t += nwaves) {
        const int v0 = t * 16;
        int vr = v0 + mr;
        if (vr >= n_nodes) vr = n_nodes - 1;

        bf16x8 a[4];
#pragma unroll
        for (int ks = 0; ks < 4; ++ks) {
            const float* src = (ks < 2) ? (x + (size_t)vr * D + ks * 32)
                                        : (agg + (size_t)vr * D + (ks - 2) * 32);
            const float* p = src + quad * 8;
            float4 lo = *(const float4*)p;
            float4 hi = *(const float4*)(p + 4);
            bf16x8 f;
            f[0] = f2bf(lo.x); f[1] = f2bf(lo.y); f[2] = f2bf(lo.z); f[3] = f2bf(lo.w);
            f[4] = f2bf(hi.x); f[5] = f2bf(hi.y); f[6] = f2bf(hi.z); f[7] = f2bf(hi.w);
            a[ks] = f;
        }

#pragma unroll
        for (int nb = 0; nb < 4; ++nb) {
            f32x4 acc = {0.f, 0.f, 0.f, 0.f};
#pragma unroll
            for (int ks = 0; ks < 4; ++ks)
                acc = __builtin_amdgcn_mfma_f32_16x16x32_bf16(a[ks], w1f[ks][nb], acc, 0, 0, 0);
#pragma unroll
            for (int r = 0; r < 4; ++r) {
                float hv = fmaxf(acc[r] + b1v[nb], 0.f);
                Hw[(quad * 4 + r) * 72 + nb * 16 + mr] = __float2bfloat16(hv);
            }
        }

        bf16x8 h[2];
#pragma unroll
        for (int ks = 0; ks < 2; ++ks)
            h[ks] = *(const bf16x8*)&Hw[mr * 72 + ks * 32 + quad * 8];

#pragma unroll
        for (int nb = 0; nb < 4; ++nb) {
            f32x4 acc = {0.f, 0.f, 0.f, 0.f};
            acc = __builtin_amdgcn_mfma_f32_16x16x32_bf16(h[0], w2f[0][nb], acc, 0, 0, 0);
            acc = __builtin_amdgcn_mfma_f32_16x16x32_bf16(h[1], w2f[1][nb], acc, 0, 0, 0);
#pragma unroll
            for (int r = 0; r < 4; ++r) {
                int vrow = v0 + quad * 4 + r;
                if (vrow < n_nodes)
                    out[(size_t)vrow * D + nb * 16 + mr] = acc[r] + b2v[nb];
            }
        }
    }
}

// ---------------------------------------------------------------------------
extern "C" void kernel_launch(void* const* d_in, const int* in_sizes, int n_in,
                              void* d_out, int out_size, void* d_ws, size_t ws_size,
                              hipStream_t stream) {
    const float* x   = (const float*)d_in[0];
    const int*   ei  = (const int*)d_in[1];
    // d_in[2] = batch (unused)
    const float* mw1 = (const float*)d_in[3];
    const float* mb1 = (const float*)d_in[4];
    const float* mw2 = (const float*)d_in[5];
    const float* mb2 = (const float*)d_in[6];
    const float* ow1 = (const float*)d_in[7];
    const float* ob1 = (const float*)d_in[8];
    const float* ow2 = (const float*)d_in[9];
    const float* ob2 = (const float*)d_in[10];

    const int n_nodes = in_sizes[0] / D;        // 100000
    const int n_edges = in_sizes[1] / 2;        // 1000000
    const int* row = ei;                        // edge_index[0]
    const int* col = ei + n_edges;              // edge_index[1]

    const int nbuckets = (n_nodes + BW - 1) >> BSHIFT;   // 782

    // ws layout
    float* m   = (float*)d_ws;                            // [n_nodes*64] f32
    float* agg = m + (size_t)n_nodes * D;                 // [n_nodes*64] f32
    unsigned int* tmp = (unsigned int*)(agg + (size_t)n_nodes * D); // [n_edges]
    int* bcount = (int*)(tmp + n_edges);                  // [nbuckets]
    int* gstart = bcount + nbuckets;                      // [nbuckets]
    int* gcur   = gstart + nbuckets;                      // [nbuckets]
    const size_t need = (size_t)n_nodes * D * 8 + (size_t)n_edges * 4
                      + (size_t)nbuckets * 12;

    const int ntiles = (n_nodes + 15) / 16;
    const int nblk   = (ntiles + 3) / 4;

    msg_kernel<<<nblk, 256, 0, stream>>>(x, mw1, mb1, mw2, mb2, m, n_nodes);

    const bool shape_ok = (n_nodes < (1 << 17)) && (nbuckets <= MAXB);

    if (ws_size >= need && shape_ok) {
        hipMemsetAsync(bcount, 0, (size_t)nbuckets * sizeof(int), stream);
        bhist_kernel<<<256, 256, 0, stream>>>(col, bcount, n_edges, nbuckets);
        bscan_kernel<<<1, 1024, 0, stream>>>(bcount, gstart, gcur, nbuckets);
        const int nbbin = 128;
        const int chunk = (n_edges + nbbin - 1) / nbbin;
        bin_kernel<<<nbbin, 256, 0, stream>>>(row, col, gcur, tmp,
                                              n_edges, nbuckets, chunk);
        bucket_gather_kernel<<<nbuckets, 1024, 0, stream>>>(gstart, tmp, m, agg,
                                                            n_nodes, n_edges, nbuckets);
    } else {
        hipMemsetAsync(agg, 0, (size_t)n_nodes * D * sizeof(float), stream);
        const int nwaves_s = (n_edges + 63) / 64;
        scatter_kernel<<<(nwaves_s + 3) / 4, 256, 0, stream>>>(row, col, m, agg, n_edges);
    }

    out_kernel<<<nblk, 256, 0, stream>>>(x, agg, ow1, ob1, ow2, ob2,
                                         (float*)d_out, n_nodes);
}

// Round 12
// 220.848 us; speedup vs baseline: 2.7331x; 1.0187x over previous
//
#include <hip/hip_runtime.h>
#include <hip/hip_bf16.h>

#define D 64
#define BSHIFT 7
#define BW (1 << BSHIFT)          // bucket width: 128 destination nodes
#define MAXB 1024                 // max buckets (bscan is a 1024-thread scan)
#define CAP 8192                  // max edges sorted per LDS round (32 KB)

typedef __attribute__((ext_vector_type(8))) short bf16x8;   // 8 bf16 in 4 VGPRs
typedef __attribute__((ext_vector_type(4))) float f32x4;

__device__ __forceinline__ short f2bf(float f) {
    __hip_bfloat16 h = __float2bfloat16(f);
    return *reinterpret_cast<short*>(&h);
}

// ---------------------------------------------------------------------------
// K1: per-node message MLP via MFMA.  m[v] = relu(x[v]@W1 + b1)@W2 + b2
// m stored bf16: halves the gather's random fetch (accuracy validated in R8).
// ---------------------------------------------------------------------------
__global__ __launch_bounds__(256) void msg_kernel(
    const float* __restrict__ x,
    const float* __restrict__ w1, const float* __restrict__ b1,
    const float* __restrict__ w2, const float* __restrict__ b2,
    __hip_bfloat16* __restrict__ m, int n_nodes)
{
    __shared__ __align__(16) __hip_bfloat16 sH[4][16 * 72];

    const int lane = threadIdx.x & 63;
    const int wslot = threadIdx.x >> 6;
    const int mr   = lane & 15;
    const int quad = lane >> 4;

    bf16x8 w1f[2][4], w2f[2][4];
    float  b1v[4], b2v[4];
#pragma unroll
    for (int ks = 0; ks < 2; ++ks)
#pragma unroll
        for (int nb = 0; nb < 4; ++nb) {
            bf16x8 f1, f2;
#pragma unroll
            for (int j = 0; j < 8; ++j) {
                int k = ks * 32 + quad * 8 + j;
                f1[j] = f2bf(w1[k * D + nb * 16 + mr]);
                f2[j] = f2bf(w2[k * D + nb * 16 + mr]);
            }
            w1f[ks][nb] = f1;
            w2f[ks][nb] = f2;
        }
#pragma unroll
    for (int nb = 0; nb < 4; ++nb) {
        b1v[nb] = b1[nb * 16 + mr];
        b2v[nb] = b2[nb * 16 + mr];
    }

    __hip_bfloat16* Hw = sH[wslot];
    const int wid    = (blockIdx.x * blockDim.x + threadIdx.x) >> 6;
    const int nwaves = (gridDim.x * blockDim.x) >> 6;
    const int ntiles = (n_nodes + 15) >> 4;

    for (int t = wid; t < ntiles; t += nwaves) {
        const int v0 = t * 16;
        int vr = v0 + mr;
        if (vr >= n_nodes) vr = n_nodes - 1;

        bf16x8 a[2];
#pragma unroll
        for (int ks = 0; ks < 2; ++ks) {
            const float* p = x + (size_t)vr * D + ks * 32 + quad * 8;
            float4 lo = *(const float4*)p;
            float4 hi = *(const float4*)(p + 4);
            bf16x8 f;
            f[0] = f2bf(lo.x); f[1] = f2bf(lo.y); f[2] = f2bf(lo.z); f[3] = f2bf(lo.w);
            f[4] = f2bf(hi.x); f[5] = f2bf(hi.y); f[6] = f2bf(hi.z); f[7] = f2bf(hi.w);
            a[ks] = f;
        }

#pragma unroll
        for (int nb = 0; nb < 4; ++nb) {
            f32x4 acc = {0.f, 0.f, 0.f, 0.f};
            acc = __builtin_amdgcn_mfma_f32_16x16x32_bf16(a[0], w1f[0][nb], acc, 0, 0, 0);
            acc = __builtin_amdgcn_mfma_f32_16x16x32_bf16(a[1], w1f[1][nb], acc, 0, 0, 0);
#pragma unroll
            for (int r = 0; r < 4; ++r) {
                float hv = fmaxf(acc[r] + b1v[nb], 0.f);
                Hw[(quad * 4 + r) * 72 + nb * 16 + mr] = __float2bfloat16(hv);
            }
        }

        bf16x8 h[2];
#pragma unroll
        for (int ks = 0; ks < 2; ++ks)
            h[ks] = *(const bf16x8*)&Hw[mr * 72 + ks * 32 + quad * 8];

#pragma unroll
        for (int nb = 0; nb < 4; ++nb) {
            f32x4 acc = {0.f, 0.f, 0.f, 0.f};
            acc = __builtin_amdgcn_mfma_f32_16x16x32_bf16(h[0], w2f[0][nb], acc, 0, 0, 0);
            acc = __builtin_amdgcn_mfma_f32_16x16x32_bf16(h[1], w2f[1][nb], acc, 0, 0, 0);
#pragma unroll
            for (int r = 0; r < 4; ++r) {
                int vrow = v0 + quad * 4 + r;
                if (vrow < n_nodes)
                    m[(size_t)vrow * D + nb * 16 + mr] =
                        __float2bfloat16(acc[r] + b2v[nb]);
            }
        }
    }
}

// ---------------------------------------------------------------------------
// Bucket-level CSR: bhist -> bscan -> bin (packed (c_local<<17)|src per bucket).
// ---------------------------------------------------------------------------
__global__ __launch_bounds__(256) void bhist_kernel(
    const int* __restrict__ col, int* __restrict__ bcount,
    int n_edges, int nbuckets)
{
    __shared__ int h[MAXB];
    for (int i = threadIdx.x; i < nbuckets; i += 256) h[i] = 0;
    __syncthreads();
    for (int e = blockIdx.x * blockDim.x + threadIdx.x; e < n_edges;
         e += gridDim.x * blockDim.x)
        atomicAdd(&h[col[e] >> BSHIFT], 1);
    __syncthreads();
    for (int i = threadIdx.x; i < nbuckets; i += 256)
        if (h[i]) atomicAdd(&bcount[i], h[i]);
}

// 1 block: exclusive scan of bcount -> gstart (kept) and gcur (consumed by bin).
__global__ __launch_bounds__(1024) void bscan_kernel(
    const int* __restrict__ bcount, int* __restrict__ gstart,
    int* __restrict__ gcur, int nbuckets)
{
    __shared__ int tmp[1024];
    const int t = threadIdx.x;
    int v = (t < nbuckets) ? bcount[t] : 0;
    tmp[t] = v;
    __syncthreads();
    for (int off = 1; off < 1024; off <<= 1) {
        int u = (t >= off) ? tmp[t - off] : 0;
        __syncthreads();
        tmp[t] += u;
        __syncthreads();
    }
    if (t < nbuckets) {
        int e = tmp[t] - v;   // exclusive
        gstart[t] = e;
        gcur[t]   = e;
    }
}

// Bin edges by destination bucket into packed u32: (c_local<<17) | src.
__global__ __launch_bounds__(256) void bin_kernel(
    const int* __restrict__ row, const int* __restrict__ col,
    int* __restrict__ gcur, unsigned int* __restrict__ tmp,
    int n_edges, int nbuckets, int chunk)
{
    __shared__ int hist[MAXB], base[MAXB], lcur[MAXB];
    const int t = threadIdx.x;
    const int e0 = blockIdx.x * chunk;
    const int e1 = min(e0 + chunk, n_edges);

    for (int i = t; i < nbuckets; i += 256) hist[i] = 0;
    __syncthreads();
    for (int e = e0 + t; e < e1; e += 256)
        atomicAdd(&hist[col[e] >> BSHIFT], 1);
    __syncthreads();
    for (int i = t; i < nbuckets; i += 256) {
        base[i] = hist[i] ? atomicAdd(&gcur[i], hist[i]) : 0;
        lcur[i] = 0;
    }
    __syncthreads();
    for (int e = e0 + t; e < e1; e += 256) {
        int c = col[e];
        int b = c >> BSHIFT;
        int loc = atomicAdd(&lcur[b], 1);
        unsigned int val = ((unsigned int)(c & (BW - 1)) << 17)
                         | (unsigned int)row[e];
        tmp[base[b] + loc] = val;
    }
}

// ---------------------------------------------------------------------------
// K2: fused in-LDS CSR sort + register gather (R10 structure, bf16 m + agg).
// One 1024-thread block per 128-node bucket.  Int LDS histogram -> scan ->
// sorted scatter; each wave owns 8 nodes, 8-deep ILP bf16 m-row loads,
// register fp32 accumulation, bf16 agg writeback (same rounding as out's
// f2bf, so zero extra error).
// ---------------------------------------------------------------------------
__global__ __launch_bounds__(1024) void bucket_gather_kernel(
    const int* __restrict__ gstart, const unsigned int* __restrict__ tmp,
    const __hip_bfloat16* __restrict__ m, __hip_bfloat16* __restrict__ agg,
    int n_nodes, int n_edges, int nbuckets)
{
    __shared__ unsigned int sorted[CAP];   // 32 KB
    __shared__ int cnt[BW], off[BW], cur[BW];

    const int b    = blockIdx.x;
    const int t    = threadIdx.x;
    const int lane = t & 63;
    const int wv   = t >> 6;               // 0..15
    const int vbase = b << BSHIFT;

    const int start = gstart[b];
    const int end   = (b + 1 < nbuckets) ? gstart[b + 1] : n_edges;

    float acc[8];                          // wave wv owns nodes wv + 16*i
#pragma unroll
    for (int i = 0; i < 8; ++i) acc[i] = 0.f;

    for (int r0 = start; r0 < end; r0 += CAP) {
        const int r1 = min(r0 + CAP, end);

        if (t < BW) cnt[t] = 0;
        __syncthreads();

        for (int i = r0 + t; i < r1; i += 1024)
            atomicAdd(&cnt[tmp[i] >> 17], 1);
        __syncthreads();

        if (t < BW) off[t] = cnt[t];
        __syncthreads();
        for (int d = 1; d < BW; d <<= 1) {
            int u = 0;
            if (t < BW && t >= d) u = off[t - d];
            __syncthreads();
            if (t < BW) off[t] += u;
            __syncthreads();
        }
        if (t < BW) {
            int e = off[t] - cnt[t];
            off[t] = e;
            cur[t] = e;
        }
        __syncthreads();

        for (int i = r0 + t; i < r1; i += 1024) {
            unsigned int u = tmp[i];
            int pos = atomicAdd(&cur[u >> 17], 1);
            sorted[pos] = u;
        }
        __syncthreads();

#pragma unroll
        for (int i = 0; i < 8; ++i) {
            const int n  = wv + (i << 4);
            const int o0 = off[n];
            const int c  = cnt[n];
            float s = 0.f;
            for (int cs = 0; cs < c; cs += 64) {
                const int k = min(64, c - cs);
                unsigned int pv = 0;
                if (lane < k) pv = sorted[o0 + cs + lane];

                int j = 0;
                for (; j + 8 <= k; j += 8) {
                    unsigned int u[8];
                    float v[8];
#pragma unroll
                    for (int q = 0; q < 8; ++q)
                        u[q] = __builtin_amdgcn_readlane(pv, j + q);
#pragma unroll
                    for (int q = 0; q < 8; ++q)
                        v[q] = (float)m[(size_t)(u[q] & 0x1FFFFu) * D + lane];
#pragma unroll
                    for (int q = 0; q < 8; ++q)
                        s += v[q];
                }
                for (; j < k; ++j) {
                    unsigned int u = __builtin_amdgcn_readlane(pv, j);
                    s += (float)m[(size_t)(u & 0x1FFFFu) * D + lane];
                }
            }
            acc[i] += s;
        }
        __syncthreads();
    }

#pragma unroll
    for (int i = 0; i < 8; ++i) {
        const int v = vbase + wv + (i << 4);
        if (v < n_nodes)
            agg[(size_t)v * D + lane] = __float2bfloat16(acc[i]);
    }
}

// ---------------------------------------------------------------------------
// Fallback path (ws too small / shape out of range): fp32 atomic scatter,
// then convert to bf16 agg.
// ---------------------------------------------------------------------------
__global__ __launch_bounds__(256) void scatter_kernel(
    const int* __restrict__ row, const int* __restrict__ col,
    const __hip_bfloat16* __restrict__ m, float* __restrict__ aggf, int n_edges)
{
    const int lane = threadIdx.x & 63;
    const int wid  = (blockIdx.x * blockDim.x + threadIdx.x) >> 6;
    const int base = wid * 64;
    if (base >= n_edges) return;
    const int cnt = min(64, n_edges - base);

    int my_r = 0, my_c = 0;
    if (lane < cnt) { my_r = row[base + lane]; my_c = col[base + lane]; }

    for (int j = 0; j < cnt; ++j) {
        int r = __builtin_amdgcn_readlane(my_r, j);
        int c = __builtin_amdgcn_readlane(my_c, j);
        float v = (float)m[(size_t)r * D + lane];
        atomicAdd(&aggf[(size_t)c * D + lane], v);
    }
}

__global__ __launch_bounds__(256) void cvt_kernel(
    const float* __restrict__ aggf, __hip_bfloat16* __restrict__ agg, int n)
{
    int i = blockIdx.x * blockDim.x + threadIdx.x;
    if (i < n) agg[i] = __float2bfloat16(aggf[i]);
}

// ---------------------------------------------------------------------------
// K3: output MLP via MFMA.  out[v] = relu([x[v],agg[v]]@OW1 + ob1)@OW2 + ob2
// agg is bf16: direct 16B fragment loads, no conversion.
// ---------------------------------------------------------------------------
__global__ __launch_bounds__(256) void out_kernel(
    const float* __restrict__ x, const __hip_bfloat16* __restrict__ agg,
    const float* __restrict__ w1, const float* __restrict__ b1,
    const float* __restrict__ w2, const float* __restrict__ b2,
    float* __restrict__ out, int n_nodes)
{
    __shared__ __align__(16) __hip_bfloat16 sH[4][16 * 72];

    const int lane = threadIdx.x & 63;
    const int wslot = threadIdx.x >> 6;
    const int mr   = lane & 15;
    const int quad = lane >> 4;

    bf16x8 w1f[4][4], w2f[2][4];
    float  b1v[4], b2v[4];
#pragma unroll
    for (int ks = 0; ks < 4; ++ks)
#pragma unroll
        for (int nb = 0; nb < 4; ++nb) {
            bf16x8 f;
#pragma unroll
            for (int j = 0; j < 8; ++j) {
                int k = ks * 32 + quad * 8 + j;
                f[j] = f2bf(w1[k * D + nb * 16 + mr]);
            }
            w1f[ks][nb] = f;
        }
#pragma unroll
    for (int ks = 0; ks < 2; ++ks)
#pragma unroll
        for (int nb = 0; nb < 4; ++nb) {
            bf16x8 f;
#pragma unroll
            for (int j = 0; j < 8; ++j) {
                int k = ks * 32 + quad * 8 + j;
                f[j] = f2bf(w2[k * D + nb * 16 + mr]);
            }
            w2f[ks][nb] = f;
        }
#pragma unroll
    for (int nb = 0; nb < 4; ++nb) {
        b1v[nb] = b1[nb * 16 + mr];
        b2v[nb] = b2[nb * 16 + mr];
    }

    __hip_bfloat16* Hw = sH[wslot];
    const int wid    = (blockIdx.x * blockDim.x + threadIdx.x) >> 6;
    const int nwaves = (gridDim.x * blockDim.x) >> 6;
    const int ntiles = (n_nodes + 15) >> 4;

    for (int t = wid; t < ntiles; t += nwaves) {
        const int v0 = t * 16;
        int vr = v0 + mr;
        if (vr >= n_nodes) vr = n_nodes - 1;

        bf16x8 a[4];
#pragma unroll
        for (int ks = 0; ks < 2; ++ks) {
            const float* p = x + (size_t)vr * D + ks * 32 + quad * 8;
            float4 lo = *(const float4*)p;
            float4 hi = *(const float4*)(p + 4);
            bf16x8 f;
            f[0] = f2bf(lo.x); f[1] = f2bf(lo.y); f[2] = f2bf(lo.z); f[3] = f2bf(lo.w);
            f[4] = f2bf(hi.x); f[5] = f2bf(hi.y); f[6] = f2bf(hi.z); f[7] = f2bf(hi.w);
            a[ks] = f;
        }
#pragma unroll
        for (int ks = 2; ks < 4; ++ks)
            a[ks] = *(const bf16x8*)&agg[(size_t)vr * D + (ks - 2) * 32 + quad * 8];

#pragma unroll
        for (int nb = 0; nb < 4; ++nb) {
            f32x4 acc = {0.f, 0.f, 0.f, 0.f};
#pragma unroll
            for (int ks = 0; ks < 4; ++ks)
                acc = __builtin_amdgcn_mfma_f32_16x16x32_bf16(a[ks], w1f[ks][nb], acc, 0, 0, 0);
#pragma unroll
            for (int r = 0; r < 4; ++r) {
                float hv = fmaxf(acc[r] + b1v[nb], 0.f);
                Hw[(quad * 4 + r) * 72 + nb * 16 + mr] = __float2bfloat16(hv);
            }
        }

        bf16x8 h[2];
#pragma unroll
        for (int ks = 0; ks < 2; ++ks)
            h[ks] = *(const bf16x8*)&Hw[mr * 72 + ks * 32 + quad * 8];

#pragma unroll
        for (int nb = 0; nb < 4; ++nb) {
            f32x4 acc = {0.f, 0.f, 0.f, 0.f};
            acc = __builtin_amdgcn_mfma_f32_16x16x32_bf16(h[0], w2f[0][nb], acc, 0, 0, 0);
            acc = __builtin_amdgcn_mfma_f32_16x16x32_bf16(h[1], w2f[1][nb], acc, 0, 0, 0);
#pragma unroll
            for (int r = 0; r < 4; ++r) {
                int vrow = v0 + quad * 4 + r;
                if (vrow < n_nodes)
                    out[(size_t)vrow * D + nb * 16 + mr] = acc[r] + b2v[nb];
            }
        }
    }
}

// ---------------------------------------------------------------------------
extern "C" void kernel_launch(void* const* d_in, const int* in_sizes, int n_in,
                              void* d_out, int out_size, void* d_ws, size_t ws_size,
                              hipStream_t stream) {
    const float* x   = (const float*)d_in[0];
    const int*   ei  = (const int*)d_in[1];
    // d_in[2] = batch (unused)
    const float* mw1 = (const float*)d_in[3];
    const float* mb1 = (const float*)d_in[4];
    const float* mw2 = (const float*)d_in[5];
    const float* mb2 = (const float*)d_in[6];
    const float* ow1 = (const float*)d_in[7];
    const float* ob1 = (const float*)d_in[8];
    const float* ow2 = (const float*)d_in[9];
    const float* ob2 = (const float*)d_in[10];

    const int n_nodes = in_sizes[0] / D;        // 100000
    const int n_edges = in_sizes[1] / 2;        // 1000000
    const int* row = ei;                        // edge_index[0]
    const int* col = ei + n_edges;              // edge_index[1]

    const int nbuckets = (n_nodes + BW - 1) >> BSHIFT;   // 782

    // ws layout
    __hip_bfloat16* m   = (__hip_bfloat16*)d_ws;               // [N*64] bf16
    __hip_bfloat16* agg = m + (size_t)n_nodes * D;             // [N*64] bf16
    unsigned int* tmp   = (unsigned int*)(agg + (size_t)n_nodes * D); // [E] u32
    int* bcount = (int*)(tmp + n_edges);                       // [nbuckets]
    int* gstart = bcount + nbuckets;                           // [nbuckets]
    int* gcur   = gstart + nbuckets;                           // [nbuckets]
    float* aggf = (float*)tmp;                                 // fallback only
    const size_t need = (size_t)n_nodes * D * 4 + (size_t)n_edges * 4
                      + (size_t)nbuckets * 12;

    const int ntiles = (n_nodes + 15) / 16;
    const int nblk   = (ntiles + 3) / 4;

    msg_kernel<<<nblk, 256, 0, stream>>>(x, mw1, mb1, mw2, mb2, m, n_nodes);

    const bool shape_ok = (n_nodes < (1 << 17)) && (nbuckets <= MAXB);

    if (ws_size >= need && shape_ok) {
        hipMemsetAsync(bcount, 0, (size_t)nbuckets * sizeof(int), stream);
        bhist_kernel<<<256, 256, 0, stream>>>(col, bcount, n_edges, nbuckets);
        bscan_kernel<<<1, 1024, 0, stream>>>(bcount, gstart, gcur, nbuckets);
        const int nbbin = 128;
        const int chunk = (n_edges + nbbin - 1) / nbbin;
        bin_kernel<<<nbbin, 256, 0, stream>>>(row, col, gcur, tmp,
                                              n_edges, nbuckets, chunk);
        bucket_gather_kernel<<<nbuckets, 1024, 0, stream>>>(gstart, tmp, m, agg,
                                                            n_nodes, n_edges, nbuckets);
    } else {
        hipMemsetAsync(aggf, 0, (size_t)n_nodes * D * sizeof(float), stream);
        const int nwaves_s = (n_edges + 63) / 64;
        scatter_kernel<<<(nwaves_s + 3) / 4, 256, 0, stream>>>(row, col, m, aggf, n_edges);
        cvt_kernel<<<((n_nodes * D) + 255) / 256, 256, 0, stream>>>(aggf, agg, n_nodes * D);
    }

    out_kernel<<<nblk, 256, 0, stream>>>(x, agg, ow1, ob1, ow2, ob2,
                                         (float*)d_out, n_nodes);
}

// Round 13
// 210.574 us; speedup vs baseline: 2.8664x; 1.0488x over previous
//
#include <hip/hip_runtime.h>
#include <hip/hip_bf16.h>

#define D 64
#define BSHIFT 7
#define BW (1 << BSHIFT)          // bucket width: 128 destination nodes
#define MAXB 1024                 // max buckets (bscan is a 1024-thread scan)
#define CAP 8192                  // max edges sorted per LDS round (32 KB)

typedef __attribute__((ext_vector_type(8))) short bf16x8;   // 8 bf16 in 4 VGPRs
typedef __attribute__((ext_vector_type(4))) float f32x4;

__device__ __forceinline__ short f2bf(float f) {
    __hip_bfloat16 h = __float2bfloat16(f);
    return *reinterpret_cast<short*>(&h);
}

// ---------------------------------------------------------------------------
// K1: per-node message MLP via MFMA.  m[v] = relu(x[v]@W1 + b1)@W2 + b2
// Weight fragments hoisted to registers ONCE per wave; grid sized so each
// wave processes ~3 tiles (prologue of ~128 scalar loads amortized — at the
// old 1-tile-per-wave grid the prologue dominated the kernel).
// ---------------------------------------------------------------------------
__global__ __launch_bounds__(256) void msg_kernel(
    const float* __restrict__ x,
    const float* __restrict__ w1, const float* __restrict__ b1,
    const float* __restrict__ w2, const float* __restrict__ b2,
    __hip_bfloat16* __restrict__ m, int n_nodes)
{
    __shared__ __align__(16) __hip_bfloat16 sH[4][16 * 72];

    const int lane = threadIdx.x & 63;
    const int wslot = threadIdx.x >> 6;
    const int mr   = lane & 15;
    const int quad = lane >> 4;

    bf16x8 w1f[2][4], w2f[2][4];
    float  b1v[4], b2v[4];
#pragma unroll
    for (int ks = 0; ks < 2; ++ks)
#pragma unroll
        for (int nb = 0; nb < 4; ++nb) {
            bf16x8 f1, f2;
#pragma unroll
            for (int j = 0; j < 8; ++j) {
                int k = ks * 32 + quad * 8 + j;
                f1[j] = f2bf(w1[k * D + nb * 16 + mr]);
                f2[j] = f2bf(w2[k * D + nb * 16 + mr]);
            }
            w1f[ks][nb] = f1;
            w2f[ks][nb] = f2;
        }
#pragma unroll
    for (int nb = 0; nb < 4; ++nb) {
        b1v[nb] = b1[nb * 16 + mr];
        b2v[nb] = b2[nb * 16 + mr];
    }

    __hip_bfloat16* Hw = sH[wslot];
    const int wid    = (blockIdx.x * blockDim.x + threadIdx.x) >> 6;
    const int nwaves = (gridDim.x * blockDim.x) >> 6;
    const int ntiles = (n_nodes + 15) >> 4;

    for (int t = wid; t < ntiles; t += nwaves) {
        const int v0 = t * 16;
        int vr = v0 + mr;
        if (vr >= n_nodes) vr = n_nodes - 1;

        bf16x8 a[2];
#pragma unroll
        for (int ks = 0; ks < 2; ++ks) {
            const float* p = x + (size_t)vr * D + ks * 32 + quad * 8;
            float4 lo = *(const float4*)p;
            float4 hi = *(const float4*)(p + 4);
            bf16x8 f;
            f[0] = f2bf(lo.x); f[1] = f2bf(lo.y); f[2] = f2bf(lo.z); f[3] = f2bf(lo.w);
            f[4] = f2bf(hi.x); f[5] = f2bf(hi.y); f[6] = f2bf(hi.z); f[7] = f2bf(hi.w);
            a[ks] = f;
        }

#pragma unroll
        for (int nb = 0; nb < 4; ++nb) {
            f32x4 acc = {0.f, 0.f, 0.f, 0.f};
            acc = __builtin_amdgcn_mfma_f32_16x16x32_bf16(a[0], w1f[0][nb], acc, 0, 0, 0);
            acc = __builtin_amdgcn_mfma_f32_16x16x32_bf16(a[1], w1f[1][nb], acc, 0, 0, 0);
#pragma unroll
            for (int r = 0; r < 4; ++r) {
                float hv = fmaxf(acc[r] + b1v[nb], 0.f);
                Hw[(quad * 4 + r) * 72 + nb * 16 + mr] = __float2bfloat16(hv);
            }
        }

        bf16x8 h[2];
#pragma unroll
        for (int ks = 0; ks < 2; ++ks)
            h[ks] = *(const bf16x8*)&Hw[mr * 72 + ks * 32 + quad * 8];

#pragma unroll
        for (int nb = 0; nb < 4; ++nb) {
            f32x4 acc = {0.f, 0.f, 0.f, 0.f};
            acc = __builtin_amdgcn_mfma_f32_16x16x32_bf16(h[0], w2f[0][nb], acc, 0, 0, 0);
            acc = __builtin_amdgcn_mfma_f32_16x16x32_bf16(h[1], w2f[1][nb], acc, 0, 0, 0);
#pragma unroll
            for (int r = 0; r < 4; ++r) {
                int vrow = v0 + quad * 4 + r;
                if (vrow < n_nodes)
                    m[(size_t)vrow * D + nb * 16 + mr] =
                        __float2bfloat16(acc[r] + b2v[nb]);
            }
        }
    }
}

// ---------------------------------------------------------------------------
// Bucket-level CSR: bhist -> bscan -> bin (packed (c_local<<17)|src per bucket).
// ---------------------------------------------------------------------------
__global__ __launch_bounds__(256) void bhist_kernel(
    const int* __restrict__ col, int* __restrict__ bcount,
    int n_edges, int nbuckets)
{
    __shared__ int h[MAXB];
    for (int i = threadIdx.x; i < nbuckets; i += 256) h[i] = 0;
    __syncthreads();
    for (int e = blockIdx.x * blockDim.x + threadIdx.x; e < n_edges;
         e += gridDim.x * blockDim.x)
        atomicAdd(&h[col[e] >> BSHIFT], 1);
    __syncthreads();
    for (int i = threadIdx.x; i < nbuckets; i += 256)
        if (h[i]) atomicAdd(&bcount[i], h[i]);
}

// 1 block: exclusive scan of bcount -> gstart (kept) and gcur (consumed by bin).
__global__ __launch_bounds__(1024) void bscan_kernel(
    const int* __restrict__ bcount, int* __restrict__ gstart,
    int* __restrict__ gcur, int nbuckets)
{
    __shared__ int tmp[1024];
    const int t = threadIdx.x;
    int v = (t < nbuckets) ? bcount[t] : 0;
    tmp[t] = v;
    __syncthreads();
    for (int off = 1; off < 1024; off <<= 1) {
        int u = (t >= off) ? tmp[t - off] : 0;
        __syncthreads();
        tmp[t] += u;
        __syncthreads();
    }
    if (t < nbuckets) {
        int e = tmp[t] - v;   // exclusive
        gstart[t] = e;
        gcur[t]   = e;
    }
}

// Bin edges by destination bucket into packed u32: (c_local<<17) | src.
__global__ __launch_bounds__(256) void bin_kernel(
    const int* __restrict__ row, const int* __restrict__ col,
    int* __restrict__ gcur, unsigned int* __restrict__ tmp,
    int n_edges, int nbuckets, int chunk)
{
    __shared__ int hist[MAXB], base[MAXB], lcur[MAXB];
    const int t = threadIdx.x;
    const int e0 = blockIdx.x * chunk;
    const int e1 = min(e0 + chunk, n_edges);

    for (int i = t; i < nbuckets; i += 256) hist[i] = 0;
    __syncthreads();
    for (int e = e0 + t; e < e1; e += 256)
        atomicAdd(&hist[col[e] >> BSHIFT], 1);
    __syncthreads();
    for (int i = t; i < nbuckets; i += 256) {
        base[i] = hist[i] ? atomicAdd(&gcur[i], hist[i]) : 0;
        lcur[i] = 0;
    }
    __syncthreads();
    for (int e = e0 + t; e < e1; e += 256) {
        int c = col[e];
        int b = c >> BSHIFT;
        int loc = atomicAdd(&lcur[b], 1);
        unsigned int val = ((unsigned int)(c & (BW - 1)) << 17)
                         | (unsigned int)row[e];
        tmp[base[b] + loc] = val;
    }
}

// ---------------------------------------------------------------------------
// K2: fused in-LDS CSR sort + register gather (validated R10/R11 structure).
// ---------------------------------------------------------------------------
__global__ __launch_bounds__(1024) void bucket_gather_kernel(
    const int* __restrict__ gstart, const unsigned int* __restrict__ tmp,
    const __hip_bfloat16* __restrict__ m, __hip_bfloat16* __restrict__ agg,
    int n_nodes, int n_edges, int nbuckets)
{
    __shared__ unsigned int sorted[CAP];   // 32 KB
    __shared__ int cnt[BW], off[BW], cur[BW];

    const int b    = blockIdx.x;
    const int t    = threadIdx.x;
    const int lane = t & 63;
    const int wv   = t >> 6;               // 0..15
    const int vbase = b << BSHIFT;

    const int start = gstart[b];
    const int end   = (b + 1 < nbuckets) ? gstart[b + 1] : n_edges;

    float acc[8];                          // wave wv owns nodes wv + 16*i
#pragma unroll
    for (int i = 0; i < 8; ++i) acc[i] = 0.f;

    for (int r0 = start; r0 < end; r0 += CAP) {
        const int r1 = min(r0 + CAP, end);

        if (t < BW) cnt[t] = 0;
        __syncthreads();

        for (int i = r0 + t; i < r1; i += 1024)
            atomicAdd(&cnt[tmp[i] >> 17], 1);
        __syncthreads();

        if (t < BW) off[t] = cnt[t];
        __syncthreads();
        for (int d = 1; d < BW; d <<= 1) {
            int u = 0;
            if (t < BW && t >= d) u = off[t - d];
            __syncthreads();
            if (t < BW) off[t] += u;
            __syncthreads();
        }
        if (t < BW) {
            int e = off[t] - cnt[t];
            off[t] = e;
            cur[t] = e;
        }
        __syncthreads();

        for (int i = r0 + t; i < r1; i += 1024) {
            unsigned int u = tmp[i];
            int pos = atomicAdd(&cur[u >> 17], 1);
            sorted[pos] = u;
        }
        __syncthreads();

#pragma unroll
        for (int i = 0; i < 8; ++i) {
            const int n  = wv + (i << 4);
            const int o0 = off[n];
            const int c  = cnt[n];
            float s = 0.f;
            for (int cs = 0; cs < c; cs += 64) {
                const int k = min(64, c - cs);
                unsigned int pv = 0;
                if (lane < k) pv = sorted[o0 + cs + lane];

                int j = 0;
                for (; j + 8 <= k; j += 8) {
                    unsigned int u[8];
                    float v[8];
#pragma unroll
                    for (int q = 0; q < 8; ++q)
                        u[q] = __builtin_amdgcn_readlane(pv, j + q);
#pragma unroll
                    for (int q = 0; q < 8; ++q)
                        v[q] = (float)m[(size_t)(u[q] & 0x1FFFFu) * D + lane];
#pragma unroll
                    for (int q = 0; q < 8; ++q)
                        s += v[q];
                }
                for (; j < k; ++j) {
                    unsigned int u = __builtin_amdgcn_readlane(pv, j);
                    s += (float)m[(size_t)(u & 0x1FFFFu) * D + lane];
                }
            }
            acc[i] += s;
        }
        __syncthreads();
    }

#pragma unroll
    for (int i = 0; i < 8; ++i) {
        const int v = vbase + wv + (i << 4);
        if (v < n_nodes)
            agg[(size_t)v * D + lane] = __float2bfloat16(acc[i]);
    }
}

// ---------------------------------------------------------------------------
// Fallback path (ws too small / shape out of range): fp32 atomic scatter,
// then convert to bf16 agg.
// ---------------------------------------------------------------------------
__global__ __launch_bounds__(256) void scatter_kernel(
    const int* __restrict__ row, const int* __restrict__ col,
    const __hip_bfloat16* __restrict__ m, float* __restrict__ aggf, int n_edges)
{
    const int lane = threadIdx.x & 63;
    const int wid  = (blockIdx.x * blockDim.x + threadIdx.x) >> 6;
    const int base = wid * 64;
    if (base >= n_edges) return;
    const int cnt = min(64, n_edges - base);

    int my_r = 0, my_c = 0;
    if (lane < cnt) { my_r = row[base + lane]; my_c = col[base + lane]; }

    for (int j = 0; j < cnt; ++j) {
        int r = __builtin_amdgcn_readlane(my_r, j);
        int c = __builtin_amdgcn_readlane(my_c, j);
        float v = (float)m[(size_t)r * D + lane];
        atomicAdd(&aggf[(size_t)c * D + lane], v);
    }
}

__global__ __launch_bounds__(256) void cvt_kernel(
    const float* __restrict__ aggf, __hip_bfloat16* __restrict__ agg, int n)
{
    int i = blockIdx.x * blockDim.x + threadIdx.x;
    if (i < n) agg[i] = __float2bfloat16(aggf[i]);
}

// ---------------------------------------------------------------------------
// K3: output MLP via MFMA.  out[v] = relu([x[v],agg[v]]@OW1 + ob1)@OW2 + ob2
// Same prologue-amortization: grid-stride over ~3 tiles per wave.
// ---------------------------------------------------------------------------
__global__ __launch_bounds__(256) void out_kernel(
    const float* __restrict__ x, const __hip_bfloat16* __restrict__ agg,
    const float* __restrict__ w1, const float* __restrict__ b1,
    const float* __restrict__ w2, const float* __restrict__ b2,
    float* __restrict__ out, int n_nodes)
{
    __shared__ __align__(16) __hip_bfloat16 sH[4][16 * 72];

    const int lane = threadIdx.x & 63;
    const int wslot = threadIdx.x >> 6;
    const int mr   = lane & 15;
    const int quad = lane >> 4;

    bf16x8 w1f[4][4], w2f[2][4];
    float  b1v[4], b2v[4];
#pragma unroll
    for (int ks = 0; ks < 4; ++ks)
#pragma unroll
        for (int nb = 0; nb < 4; ++nb) {
            bf16x8 f;
#pragma unroll
            for (int j = 0; j < 8; ++j) {
                int k = ks * 32 + quad * 8 + j;
                f[j] = f2bf(w1[k * D + nb * 16 + mr]);
            }
            w1f[ks][nb] = f;
        }
#pragma unroll
    for (int ks = 0; ks < 2; ++ks)
#pragma unroll
        for (int nb = 0; nb < 4; ++nb) {
            bf16x8 f;
#pragma unroll
            for (int j = 0; j < 8; ++j) {
                int k = ks * 32 + quad * 8 + j;
                f[j] = f2bf(w2[k * D + nb * 16 + mr]);
            }
            w2f[ks][nb] = f;
        }
#pragma unroll
    for (int nb = 0; nb < 4; ++nb) {
        b1v[nb] = b1[nb * 16 + mr];
        b2v[nb] = b2[nb * 16 + mr];
    }

    __hip_bfloat16* Hw = sH[wslot];
    const int wid    = (blockIdx.x * blockDim.x + threadIdx.x) >> 6;
    const int nwaves = (gridDim.x * blockDim.x) >> 6;
    const int ntiles = (n_nodes + 15) >> 4;

    for (int t = wid; t < ntiles; t += nwaves) {
        const int v0 = t * 16;
        int vr = v0 + mr;
        if (vr >= n_nodes) vr = n_nodes - 1;

        bf16x8 a[4];
#pragma unroll
        for (int ks = 0; ks < 2; ++ks) {
            const float* p = x + (size_t)vr * D + ks * 32 + quad * 8;
            float4 lo = *(const float4*)p;
            float4 hi = *(const float4*)(p + 4);
            bf16x8 f;
            f[0] = f2bf(lo.x); f[1] = f2bf(lo.y); f[2] = f2bf(lo.z); f[3] = f2bf(lo.w);
            f[4] = f2bf(hi.x); f[5] = f2bf(hi.y); f[6] = f2bf(hi.z); f[7] = f2bf(hi.w);
            a[ks] = f;
        }
#pragma unroll
        for (int ks = 2; ks < 4; ++ks)
            a[ks] = *(const bf16x8*)&agg[(size_t)vr * D + (ks - 2) * 32 + quad * 8];

#pragma unroll
        for (int nb = 0; nb < 4; ++nb) {
            f32x4 acc = {0.f, 0.f, 0.f, 0.f};
#pragma unroll
            for (int ks = 0; ks < 4; ++ks)
                acc = __builtin_amdgcn_mfma_f32_16x16x32_bf16(a[ks], w1f[ks][nb], acc, 0, 0, 0);
#pragma unroll
            for (int r = 0; r < 4; ++r) {
                float hv = fmaxf(acc[r] + b1v[nb], 0.f);
                Hw[(quad * 4 + r) * 72 + nb * 16 + mr] = __float2bfloat16(hv);
            }
        }

        bf16x8 h[2];
#pragma unroll
        for (int ks = 0; ks < 2; ++ks)
            h[ks] = *(const bf16x8*)&Hw[mr * 72 + ks * 32 + quad * 8];

#pragma unroll
        for (int nb = 0; nb < 4; ++nb) {
            f32x4 acc = {0.f, 0.f, 0.f, 0.f};
            acc = __builtin_amdgcn_mfma_f32_16x16x32_bf16(h[0], w2f[0][nb], acc, 0, 0, 0);
            acc = __builtin_amdgcn_mfma_f32_16x16x32_bf16(h[1], w2f[1][nb], acc, 0, 0, 0);
#pragma unroll
            for (int r = 0; r < 4; ++r) {
                int vrow = v0 + quad * 4 + r;
                if (vrow < n_nodes)
                    out[(size_t)vrow * D + nb * 16 + mr] = acc[r] + b2v[nb];
            }
        }
    }
}

// ---------------------------------------------------------------------------
extern "C" void kernel_launch(void* const* d_in, const int* in_sizes, int n_in,
                              void* d_out, int out_size, void* d_ws, size_t ws_size,
                              hipStream_t stream) {
    const float* x   = (const float*)d_in[0];
    const int*   ei  = (const int*)d_in[1];
    // d_in[2] = batch (unused)
    const float* mw1 = (const float*)d_in[3];
    const float* mb1 = (const float*)d_in[4];
    const float* mw2 = (const float*)d_in[5];
    const float* mb2 = (const float*)d_in[6];
    const float* ow1 = (const float*)d_in[7];
    const float* ob1 = (const float*)d_in[8];
    const float* ow2 = (const float*)d_in[9];
    const float* ob2 = (const float*)d_in[10];

    const int n_nodes = in_sizes[0] / D;        // 100000
    const int n_edges = in_sizes[1] / 2;        // 1000000
    const int* row = ei;                        // edge_index[0]
    const int* col = ei + n_edges;              // edge_index[1]

    const int nbuckets = (n_nodes + BW - 1) >> BSHIFT;   // 782

    // ws layout
    __hip_bfloat16* m   = (__hip_bfloat16*)d_ws;               // [N*64] bf16
    __hip_bfloat16* agg = m + (size_t)n_nodes * D;             // [N*64] bf16
    unsigned int* tmp   = (unsigned int*)(agg + (size_t)n_nodes * D); // [E] u32
    int* bcount = (int*)(tmp + n_edges);                       // [nbuckets]
    int* gstart = bcount + nbuckets;                           // [nbuckets]
    int* gcur   = gstart + nbuckets;                           // [nbuckets]
    float* aggf = (float*)tmp;                                 // fallback only
    const size_t need = (size_t)n_nodes * D * 4 + (size_t)n_edges * 4
                      + (size_t)nbuckets * 12;

    const int ntiles = (n_nodes + 15) / 16;
    // prologue amortization: ~3 tiles per wave (was 1 tile/wave at full grid)
    int nblk = (ntiles + 3) / 4;
    if (nblk > 512) nblk = 512;

    msg_kernel<<<nblk, 256, 0, stream>>>(x, mw1, mb1, mw2, mb2, m, n_nodes);

    const bool shape_ok = (n_nodes < (1 << 17)) && (nbuckets <= MAXB);

    if (ws_size >= need && shape_ok) {
        hipMemsetAsync(bcount, 0, (size_t)nbuckets * sizeof(int), stream);
        bhist_kernel<<<256, 256, 0, stream>>>(col, bcount, n_edges, nbuckets);
        bscan_kernel<<<1, 1024, 0, stream>>>(bcount, gstart, gcur, nbuckets);
        const int nbbin = 128;
        const int chunk = (n_edges + nbbin - 1) / nbbin;
        bin_kernel<<<nbbin, 256, 0, stream>>>(row, col, gcur, tmp,
                                              n_edges, nbuckets, chunk);
        bucket_gather_kernel<<<nbuckets, 1024, 0, stream>>>(gstart, tmp, m, agg,
                                                            n_nodes, n_edges, nbuckets);
    } else {
        hipMemsetAsync(aggf, 0, (size_t)n_nodes * D * sizeof(float), stream);
        const int nwaves_s = (n_edges + 63) / 64;
        scatter_kernel<<<(nwaves_s + 3) / 4, 256, 0, stream>>>(row, col, m, aggf, n_edges);
        cvt_kernel<<<((n_nodes * D) + 255) / 256, 256, 0, stream>>>(aggf, agg, n_nodes * D);
    }

    out_kernel<<<nblk, 256, 0, stream>>>(x, agg, ow1, ob1, ow2, ob2,
                                         (float*)d_out, n_nodes);
}